// Round 1
// baseline (510.557 us; speedup 1.0000x reference)
//
#include <hip/hip_runtime.h>
#include <stdint.h>

#define DEVI __device__ __forceinline__

typedef __attribute__((ext_vector_type(8))) short bf16x8;
typedef __attribute__((ext_vector_type(4))) float f32x4;
typedef __attribute__((ext_vector_type(4))) unsigned short u16x4;
typedef __attribute__((ext_vector_type(8))) unsigned short u16x8;

// round-to-nearest-even f32 -> bf16 (inputs are normal floats, no NaN handling needed)
DEVI unsigned short f2bf(float f) {
    union { float f; unsigned u; } v; v.f = f;
    unsigned r = v.u + 0x7fffu + ((v.u >> 16) & 1u);
    return (unsigned short)(r >> 16);
}

// async global->LDS, 16B per lane. LDS dest = wave-uniform base + lane*16.
DEVI void gload16(const void* g, void* lds) {
    __builtin_amdgcn_global_load_lds(
        (const __attribute__((address_space(1))) unsigned int*)(uintptr_t)g,
        (__attribute__((address_space(3))) unsigned int*)(unsigned int)(uintptr_t)lds,
        16, 0, 0);
}

// ---------------------------------------------------------------- convert
__global__ __launch_bounds__(256) void cvt_bf16(const float* __restrict__ in,
                                                unsigned short* __restrict__ out, int n4) {
    int i = blockIdx.x * 256 + threadIdx.x;
    if (i >= n4) return;
    float4 v = ((const float4*)in)[i];
    u16x4 pk;
    pk[0] = f2bf(v.x); pk[1] = f2bf(v.y); pk[2] = f2bf(v.z); pk[3] = f2bf(v.w);
    ((u16x4*)out)[i] = pk;
}

// ------------------------------------------------------------- GEMM core
// C[m][n] = sum_k A[m][k] * W[n][k]   (B^T layout; both row-major, K contiguous)
// 128x128 tile, BK=32, 4 waves in 2x2, each wave 64x64 = 4x4 fragments of 16x16x32.
DEVI void gemm_core_bt(const unsigned short* A, const unsigned short* W, int K,
                       unsigned short* As, unsigned short* Bs,
                       int m0, int n0, f32x4 acc[4][4]) {
    const int t = threadIdx.x;
    const int w = t >> 6, l = t & 63, lr = l & 15, lk = l >> 4;
    const int wr = w >> 1, wc = w & 1;
    const unsigned short* a_src = A + (size_t)(m0 + (t >> 2)) * K + (t & 3) * 8;
    const unsigned short* b_src = W + (size_t)(n0 + (t >> 2)) * K + (t & 3) * 8;
    char* as_base = (char*)As + w * 1024;
    char* bs_base = (char*)Bs + w * 1024;
#pragma unroll
    for (int i = 0; i < 4; i++)
#pragma unroll
        for (int j = 0; j < 4; j++) acc[i][j] = (f32x4){0.f, 0.f, 0.f, 0.f};

    for (int k0 = 0; k0 < K; k0 += 32) {
        gload16(a_src + k0, as_base);
        gload16(a_src + (size_t)64 * K + k0, as_base + 4096);
        gload16(b_src + k0, bs_base);
        gload16(b_src + (size_t)64 * K + k0, bs_base + 4096);
        __syncthreads();
        bf16x8 af[4], bf[4];
#pragma unroll
        for (int mi = 0; mi < 4; mi++)
            af[mi] = *(const bf16x8*)((const char*)As + (wr * 64 + mi * 16 + lr) * 64 + lk * 16);
#pragma unroll
        for (int ni = 0; ni < 4; ni++)
            bf[ni] = *(const bf16x8*)((const char*)Bs + (wc * 64 + ni * 16 + lr) * 64 + lk * 16);
#pragma unroll
        for (int mi = 0; mi < 4; mi++)
#pragma unroll
            for (int ni = 0; ni < 4; ni++)
                acc[mi][ni] = __builtin_amdgcn_mfma_f32_16x16x32_bf16(af[mi], bf[ni], acc[mi][ni], 0, 0, 0);
        __syncthreads();
    }
}

// qkv: z=0 -> q (fp32), z=1 -> k (fp32), z=2 -> v (bf16, transposed to (B,H,HD,S))
__global__ __launch_bounds__(256) void gemm_qkv(
    const unsigned short* __restrict__ A,
    const unsigned short* __restrict__ Wq16, const unsigned short* __restrict__ Wk16,
    const unsigned short* __restrict__ Wv16,
    const float* __restrict__ bq, const float* __restrict__ bk, const float* __restrict__ bv,
    float* __restrict__ qf, float* __restrict__ kf, unsigned short* __restrict__ Vt) {
    __shared__ unsigned short As[128 * 32];
    __shared__ unsigned short Bs[128 * 32];
    const int t = threadIdx.x;
    const int w = t >> 6, l = t & 63, lr = l & 15, lk = l >> 4;
    const int wr = w >> 1, wc = w & 1;
    const int n0 = blockIdx.x * 128, m0 = blockIdx.y * 128;
    const int z = blockIdx.z;
    const unsigned short* W = (z == 0) ? Wq16 : (z == 1) ? Wk16 : Wv16;
    const float* bias = (z == 0) ? bq : (z == 1) ? bk : bv;

    f32x4 acc[4][4];
    gemm_core_bt(A, W, 2048, As, Bs, m0, n0, acc);

#pragma unroll
    for (int ni = 0; ni < 4; ni++) {
        const int col = n0 + wc * 64 + ni * 16 + lr;
        const float bb = bias[col];
#pragma unroll
        for (int mi = 0; mi < 4; mi++) {
            const int row = m0 + wr * 64 + mi * 16 + lk * 4;
            if (z == 2) {
                const int h = col >> 7, d = col & 127;
                const int b = row >> 11, s = row & 2047;
                u16x4 pk;
#pragma unroll
                for (int j = 0; j < 4; j++) pk[j] = f2bf(acc[mi][ni][j] + bb);
                *(u16x4*)(Vt + ((size_t)((b * 16 + h) * 128 + d)) * 2048 + s) = pk;
            } else {
                float* out = (z == 0) ? qf : kf;
#pragma unroll
                for (int j = 0; j < 4; j++)
                    out[(size_t)(row + j) * 2048 + col] = acc[mi][ni][j] + bb;
            }
        }
    }
}

__global__ __launch_bounds__(256) void gemm_o(
    const unsigned short* __restrict__ A, const unsigned short* __restrict__ W16,
    const float* __restrict__ bo, float* __restrict__ out) {
    __shared__ unsigned short As[128 * 32];
    __shared__ unsigned short Bs[128 * 32];
    const int t = threadIdx.x;
    const int w = t >> 6, l = t & 63, lr = l & 15, lk = l >> 4;
    const int wr = w >> 1, wc = w & 1;
    const int n0 = blockIdx.x * 128, m0 = blockIdx.y * 128;
    f32x4 acc[4][4];
    gemm_core_bt(A, W16, 2048, As, Bs, m0, n0, acc);
#pragma unroll
    for (int ni = 0; ni < 4; ni++) {
        const int col = n0 + wc * 64 + ni * 16 + lr;
        const float bb = bo[col];
#pragma unroll
        for (int mi = 0; mi < 4; mi++) {
            const int row = m0 + wr * 64 + mi * 16 + lk * 4;
#pragma unroll
            for (int j = 0; j < 4; j++)
                out[(size_t)(row + j) * 2048 + col] = acc[mi][ni][j] + bb;
        }
    }
}

// ---------------------------------------------------- RMSNorm (full DIM) + RoPE
// one block per (b*S+s) row; y: 0=q, 1=k. writes bf16 (B,H,S,HD)
__global__ __launch_bounds__(256) void norm_rope(
    const float* __restrict__ qf, const float* __restrict__ kf,
    const float* __restrict__ nqw, const float* __restrict__ nkw,
    const float* __restrict__ fc, const float* __restrict__ fs,
    unsigned short* __restrict__ Qr, unsigned short* __restrict__ Kr) {
    const int row = blockIdx.x;
    const int which = blockIdx.y;
    const float* in = which ? kf : qf;
    const float* wv = which ? nkw : nqw;
    unsigned short* out = which ? Kr : Qr;
    const int t = threadIdx.x;
    const float* x = in + (size_t)row * 2048 + t * 8;
    float4 v0 = ((const float4*)x)[0];
    float4 v1 = ((const float4*)x)[1];
    float xv[8] = {v0.x, v0.y, v0.z, v0.w, v1.x, v1.y, v1.z, v1.w};
    float ss = 0.f;
#pragma unroll
    for (int e = 0; e < 8; e++) ss += xv[e] * xv[e];
#pragma unroll
    for (int m = 1; m < 64; m <<= 1) ss += __shfl_xor(ss, m, 64);
    __shared__ float red[4];
    if ((t & 63) == 0) red[t >> 6] = ss;
    __syncthreads();
    const float tot = red[0] + red[1] + red[2] + red[3];
    const float r = rsqrtf(tot * (1.0f / 2048.0f) + 1e-6f);
    const int s = row & 2047, b = row >> 11;
    const int d0 = t * 8, hd0 = d0 & 127, h = d0 >> 7;
    float4 c0 = ((const float4*)(fc + s * 128 + hd0))[0];
    float4 c1 = ((const float4*)(fc + s * 128 + hd0))[1];
    float4 s0 = ((const float4*)(fs + s * 128 + hd0))[0];
    float4 s1 = ((const float4*)(fs + s * 128 + hd0))[1];
    float4 w0 = ((const float4*)(wv + d0))[0];
    float4 w1 = ((const float4*)(wv + d0))[1];
    float wn[8] = {w0.x, w0.y, w0.z, w0.w, w1.x, w1.y, w1.z, w1.w};
    float xn[8];
#pragma unroll
    for (int e = 0; e < 8; e++) xn[e] = xv[e] * wn[e] * r;
    float o[8];
    // pair (2i,2i+1): cos=fc[s,2i], sin=fs[s,2i+1]
    o[0] = xn[0] * c0.x - xn[1] * s0.y;  o[1] = xn[0] * s0.y + xn[1] * c0.x;
    o[2] = xn[2] * c0.z - xn[3] * s0.w;  o[3] = xn[2] * s0.w + xn[3] * c0.z;
    o[4] = xn[4] * c1.x - xn[5] * s1.y;  o[5] = xn[4] * s1.y + xn[5] * c1.x;
    o[6] = xn[6] * c1.z - xn[7] * s1.w;  o[7] = xn[6] * s1.w + xn[7] * c1.z;
    u16x8 pk;
#pragma unroll
    for (int e = 0; e < 8; e++) pk[e] = f2bf(o[e]);
    *(u16x8*)(out + ((size_t)((b * 16 + h) * 2048 + s)) * 128 + hd0) = pk;
}

// -------------------------------------------------------------- flash attn
// grid (S/64, B*H); 4 waves/block, wave = 16 q rows. KV tile = 32.
// K LDS [32][128] bf16 with 16B-seg XOR swizzle seg^=(row&7)   (kills 16-way conflict)
// V LDS [128][32] bf16 (from Vt (B,H,HD,S)) with seg^=((d>>2)&3)
__global__ __launch_bounds__(256) void attn(
    const unsigned short* __restrict__ Qr, const unsigned short* __restrict__ Kr,
    const unsigned short* __restrict__ Vt, unsigned short* __restrict__ Ao) {
    __shared__ unsigned short Kl[32 * 128];
    __shared__ unsigned short Vl[128 * 32];
    __shared__ unsigned short Pl[4][16 * 32];
    const int t = threadIdx.x, w = t >> 6, l = t & 63, lr = l & 15, lk = l >> 4;
    const int bh = blockIdx.y;
    const int q0 = blockIdx.x * 64 + w * 16;
    const unsigned short* Qp = Qr + ((size_t)bh * 2048 + q0) * 128;
    bf16x8 aq[4];
#pragma unroll
    for (int ks = 0; ks < 4; ks++)
        aq[ks] = *(const bf16x8*)(Qp + lr * 128 + ks * 32 + lk * 8);

    f32x4 accO[8];
#pragma unroll
    for (int i = 0; i < 8; i++) accO[i] = (f32x4){0.f, 0.f, 0.f, 0.f};
    float mj[4] = {-1e30f, -1e30f, -1e30f, -1e30f};
    float lj[4] = {0.f, 0.f, 0.f, 0.f};
    const float scale = 0.08838834764831845f;  // 1/sqrt(128)

    const unsigned short* Kb = Kr + (size_t)bh * 2048 * 128;
    const unsigned short* Vb = Vt + (size_t)bh * 128 * 2048;
    char* kls = (char*)Kl + w * 1024;
    char* vls = (char*)Vl + w * 1024;
    const int krow = t >> 4;                  // K tile row this thread stages
    const int kseg = (t & 15) ^ (krow & 7);   // pre-swizzled source segment
    const int vrow = t >> 2;
    const int vseg = (t & 3) ^ ((t >> 4) & 3);

    for (int kv0 = 0; kv0 < 2048; kv0 += 32) {
        gload16(Kb + (size_t)(kv0 + krow) * 128 + kseg * 8, kls);
        gload16(Kb + (size_t)(kv0 + 16 + krow) * 128 + kseg * 8, kls + 4096);
        gload16(Vb + (size_t)vrow * 2048 + kv0 + vseg * 8, vls);
        gload16(Vb + (size_t)(64 + vrow) * 2048 + kv0 + vseg * 8, vls + 4096);
        __syncthreads();
        // QK^T: D[q][key], two 16-key column groups
        f32x4 sfr[2];
#pragma unroll
        for (int kc = 0; kc < 2; kc++) {
            f32x4 sa = (f32x4){0.f, 0.f, 0.f, 0.f};
            const int key = kc * 16 + lr;
#pragma unroll
            for (int ks = 0; ks < 4; ks++) {
                const int seg = (ks * 4 + lk) ^ (key & 7);
                bf16x8 bk = *(const bf16x8*)((const char*)Kl + key * 256 + seg * 16);
                sa = __builtin_amdgcn_mfma_f32_16x16x32_bf16(aq[ks], bk, sa, 0, 0, 0);
            }
#pragma unroll
            for (int j = 0; j < 4; j++) sa[j] *= scale;
            sfr[kc] = sa;
        }
        // online softmax; row = lk*4+j, cols spread over the 16 lanes (lr)
        float corr[4];
#pragma unroll
        for (int j = 0; j < 4; j++) {
            float tm = fmaxf(sfr[0][j], sfr[1][j]);
            tm = fmaxf(tm, __shfl_xor(tm, 1, 64));
            tm = fmaxf(tm, __shfl_xor(tm, 2, 64));
            tm = fmaxf(tm, __shfl_xor(tm, 4, 64));
            tm = fmaxf(tm, __shfl_xor(tm, 8, 64));
            const float mn = fmaxf(mj[j], tm);
            corr[j] = __expf(mj[j] - mn);
            const float p0 = __expf(sfr[0][j] - mn);
            const float p1 = __expf(sfr[1][j] - mn);
            mj[j] = mn;
            Pl[w][(lk * 4 + j) * 32 + lr] = f2bf(p0);
            Pl[w][(lk * 4 + j) * 32 + 16 + lr] = f2bf(p1);
            float ps = p0 + p1;
            ps += __shfl_xor(ps, 1, 64);
            ps += __shfl_xor(ps, 2, 64);
            ps += __shfl_xor(ps, 4, 64);
            ps += __shfl_xor(ps, 8, 64);
            lj[j] = lj[j] * corr[j] + ps;
        }
#pragma unroll
        for (int d0 = 0; d0 < 8; d0++)
#pragma unroll
            for (int j = 0; j < 4; j++) accO[d0][j] *= corr[j];
        // PV: A = P[q][key] (wave-private LDS bounce), B = V[key][d] from Vl[d][key]
        bf16x8 ap = *(const bf16x8*)((const char*)&Pl[w][0] + lr * 64 + lk * 16);
#pragma unroll
        for (int d0 = 0; d0 < 8; d0++) {
            const int d = d0 * 16 + lr;
            const int seg = lk ^ ((d >> 2) & 3);
            bf16x8 bv = *(const bf16x8*)((const char*)Vl + d * 64 + seg * 16);
            accO[d0] = __builtin_amdgcn_mfma_f32_16x16x32_bf16(ap, bv, accO[d0], 0, 0, 0);
        }
        __syncthreads();
    }
    // epilogue: Ao (B,S,H*HD) bf16
    const int b = bh >> 4, h = bh & 15;
    float inv[4];
#pragma unroll
    for (int j = 0; j < 4; j++) inv[j] = 1.0f / lj[j];
#pragma unroll
    for (int d0 = 0; d0 < 8; d0++)
#pragma unroll
        for (int j = 0; j < 4; j++) {
            const int row = q0 + lk * 4 + j;
            Ao[((size_t)(b * 2048 + row)) * 2048 + h * 128 + d0 * 16 + lr] =
                f2bf(accO[d0][j] * inv[j]);
        }
}

// ------------------------------------------------------------------ launch
extern "C" void kernel_launch(void* const* d_in, const int* in_sizes, int n_in,
                              void* d_out, int out_size, void* d_ws, size_t ws_size,
                              hipStream_t stream) {
    const float* hs  = (const float*)d_in[0];
    const float* fc  = (const float*)d_in[1];
    const float* fs  = (const float*)d_in[2];
    const float* Wq  = (const float*)d_in[3];
    const float* bq  = (const float*)d_in[4];
    const float* Wk  = (const float*)d_in[5];
    const float* bk  = (const float*)d_in[6];
    const float* Wv  = (const float*)d_in[7];
    const float* bv  = (const float*)d_in[8];
    const float* nqw = (const float*)d_in[9];
    const float* nkw = (const float*)d_in[10];
    const float* Wo  = (const float*)d_in[11];
    const float* bo  = (const float*)d_in[12];
    float* out = (float*)d_out;

    char* p = (char*)d_ws;
    unsigned short* hs16 = (unsigned short*)p; p += (size_t)8388608 * 2;
    unsigned short* Wq16 = (unsigned short*)p; p += (size_t)4194304 * 2;
    unsigned short* Wk16 = (unsigned short*)p; p += (size_t)4194304 * 2;
    unsigned short* Wv16 = (unsigned short*)p; p += (size_t)4194304 * 2;
    unsigned short* Wo16 = (unsigned short*)p; p += (size_t)4194304 * 2;
    float* qf = (float*)p;                     p += (size_t)8388608 * 4;
    float* kf = (float*)p;                     p += (size_t)8388608 * 4;
    unsigned short* Qr = (unsigned short*)p;   p += (size_t)8388608 * 2;
    unsigned short* Kr = (unsigned short*)p;   p += (size_t)8388608 * 2;
    unsigned short* Vt = (unsigned short*)p;   p += (size_t)8388608 * 2;
    unsigned short* Ao = (unsigned short*)p;   p += (size_t)8388608 * 2;
    (void)ws_size; (void)in_sizes; (void)n_in; (void)out_size;

    cvt_bf16<<<8192, 256, 0, stream>>>(hs, hs16, 2097152);
    cvt_bf16<<<4096, 256, 0, stream>>>(Wq, Wq16, 1048576);
    cvt_bf16<<<4096, 256, 0, stream>>>(Wk, Wk16, 1048576);
    cvt_bf16<<<4096, 256, 0, stream>>>(Wv, Wv16, 1048576);
    cvt_bf16<<<4096, 256, 0, stream>>>(Wo, Wo16, 1048576);

    gemm_qkv<<<dim3(16, 32, 3), 256, 0, stream>>>(hs16, Wq16, Wk16, Wv16,
                                                  bq, bk, bv, qf, kf, Vt);
    norm_rope<<<dim3(4096, 2), 256, 0, stream>>>(qf, kf, nqw, nkw, fc, fs, Qr, Kr);
    attn<<<dim3(32, 32), 256, 0, stream>>>(Qr, Kr, Vt, Ao);
    gemm_o<<<dim3(16, 32), 256, 0, stream>>>(Ao, Wo16, bo, out);
}

// Round 2
// 449.976 us; speedup vs baseline: 1.1346x; 1.1346x over previous
//
#include <hip/hip_runtime.h>
#include <stdint.h>

#define DEVI __device__ __forceinline__

typedef __attribute__((ext_vector_type(8))) short bf16x8;
typedef __attribute__((ext_vector_type(4))) float f32x4;
typedef __attribute__((ext_vector_type(4))) unsigned short u16x4;
typedef __attribute__((ext_vector_type(8))) unsigned short u16x8;

// round-to-nearest-even f32 -> bf16 (inputs are normal floats, no NaN handling needed)
DEVI unsigned short f2bf(float f) {
    union { float f; unsigned u; } v; v.f = f;
    unsigned r = v.u + 0x7fffu + ((v.u >> 16) & 1u);
    return (unsigned short)(r >> 16);
}

// async global->LDS, 16B per lane. LDS dest = wave-uniform base + lane*16.
DEVI void gload16(const void* g, void* lds) {
    __builtin_amdgcn_global_load_lds(
        (const __attribute__((address_space(1))) unsigned int*)(uintptr_t)g,
        (__attribute__((address_space(3))) unsigned int*)(unsigned int)(uintptr_t)lds,
        16, 0, 0);
}

// ---------------------------------------------------------------- convert
__global__ __launch_bounds__(256) void cvt_bf16(const float* __restrict__ in,
                                                unsigned short* __restrict__ out, int n4) {
    int i = blockIdx.x * 256 + threadIdx.x;
    if (i >= n4) return;
    float4 v = ((const float4*)in)[i];
    u16x4 pk;
    pk[0] = f2bf(v.x); pk[1] = f2bf(v.y); pk[2] = f2bf(v.z); pk[3] = f2bf(v.w);
    ((u16x4*)out)[i] = pk;
}

// ------------------------------------------------------------- GEMM core
// C[m][n] = sum_k A[m][k] * W[n][k]   (B^T layout; both row-major, K contiguous)
// 128x128 tile, BK=32, 4 waves in 2x2, each wave 64x64 = 4x4 fragments of 16x16x32.
DEVI void gemm_core_bt(const unsigned short* A, const unsigned short* W, int K,
                       unsigned short* As, unsigned short* Bs,
                       int m0, int n0, f32x4 acc[4][4]) {
    const int t = threadIdx.x;
    const int w = t >> 6, l = t & 63, lr = l & 15, lk = l >> 4;
    const int wr = w >> 1, wc = w & 1;
    const unsigned short* a_src = A + (size_t)(m0 + (t >> 2)) * K + (t & 3) * 8;
    const unsigned short* b_src = W + (size_t)(n0 + (t >> 2)) * K + (t & 3) * 8;
    char* as_base = (char*)As + w * 1024;
    char* bs_base = (char*)Bs + w * 1024;
#pragma unroll
    for (int i = 0; i < 4; i++)
#pragma unroll
        for (int j = 0; j < 4; j++) acc[i][j] = (f32x4){0.f, 0.f, 0.f, 0.f};

    for (int k0 = 0; k0 < K; k0 += 32) {
        gload16(a_src + k0, as_base);
        gload16(a_src + (size_t)64 * K + k0, as_base + 4096);
        gload16(b_src + k0, bs_base);
        gload16(b_src + (size_t)64 * K + k0, bs_base + 4096);
        __syncthreads();
        bf16x8 af[4], bf[4];
#pragma unroll
        for (int mi = 0; mi < 4; mi++)
            af[mi] = *(const bf16x8*)((const char*)As + (wr * 64 + mi * 16 + lr) * 64 + lk * 16);
#pragma unroll
        for (int ni = 0; ni < 4; ni++)
            bf[ni] = *(const bf16x8*)((const char*)Bs + (wc * 64 + ni * 16 + lr) * 64 + lk * 16);
#pragma unroll
        for (int mi = 0; mi < 4; mi++)
#pragma unroll
            for (int ni = 0; ni < 4; ni++)
                acc[mi][ni] = __builtin_amdgcn_mfma_f32_16x16x32_bf16(af[mi], bf[ni], acc[mi][ni], 0, 0, 0);
        __syncthreads();
    }
}

// qkv: z=0 -> q (fp32), z=1 -> k (fp32), z=2 -> v (bf16, transposed to (B,H,HD,S))
__global__ __launch_bounds__(256) void gemm_qkv(
    const unsigned short* __restrict__ A,
    const unsigned short* __restrict__ Wq16, const unsigned short* __restrict__ Wk16,
    const unsigned short* __restrict__ Wv16,
    const float* __restrict__ bq, const float* __restrict__ bk, const float* __restrict__ bv,
    float* __restrict__ qf, float* __restrict__ kf, unsigned short* __restrict__ Vt) {
    __shared__ unsigned short As[128 * 32];
    __shared__ unsigned short Bs[128 * 32];
    const int t = threadIdx.x;
    const int w = t >> 6, l = t & 63, lr = l & 15, lk = l >> 4;
    const int wr = w >> 1, wc = w & 1;
    const int n0 = blockIdx.x * 128, m0 = blockIdx.y * 128;
    const int z = blockIdx.z;
    const unsigned short* W = (z == 0) ? Wq16 : (z == 1) ? Wk16 : Wv16;
    const float* bias = (z == 0) ? bq : (z == 1) ? bk : bv;

    f32x4 acc[4][4];
    gemm_core_bt(A, W, 2048, As, Bs, m0, n0, acc);

#pragma unroll
    for (int ni = 0; ni < 4; ni++) {
        const int col = n0 + wc * 64 + ni * 16 + lr;
        const float bb = bias[col];
#pragma unroll
        for (int mi = 0; mi < 4; mi++) {
            const int row = m0 + wr * 64 + mi * 16 + lk * 4;
            if (z == 2) {
                const int h = col >> 7, d = col & 127;
                const int b = row >> 11, s = row & 2047;
                u16x4 pk;
#pragma unroll
                for (int j = 0; j < 4; j++) pk[j] = f2bf(acc[mi][ni][j] + bb);
                *(u16x4*)(Vt + ((size_t)((b * 16 + h) * 128 + d)) * 2048 + s) = pk;
            } else {
                float* out = (z == 0) ? qf : kf;
#pragma unroll
                for (int j = 0; j < 4; j++)
                    out[(size_t)(row + j) * 2048 + col] = acc[mi][ni][j] + bb;
            }
        }
    }
}

__global__ __launch_bounds__(256) void gemm_o(
    const unsigned short* __restrict__ A, const unsigned short* __restrict__ W16,
    const float* __restrict__ bo, float* __restrict__ out) {
    __shared__ unsigned short As[128 * 32];
    __shared__ unsigned short Bs[128 * 32];
    const int t = threadIdx.x;
    const int w = t >> 6, l = t & 63, lr = l & 15, lk = l >> 4;
    const int wr = w >> 1, wc = w & 1;
    const int n0 = blockIdx.x * 128, m0 = blockIdx.y * 128;
    f32x4 acc[4][4];
    gemm_core_bt(A, W16, 2048, As, Bs, m0, n0, acc);
#pragma unroll
    for (int ni = 0; ni < 4; ni++) {
        const int col = n0 + wc * 64 + ni * 16 + lr;
        const float bb = bo[col];
#pragma unroll
        for (int mi = 0; mi < 4; mi++) {
            const int row = m0 + wr * 64 + mi * 16 + lk * 4;
#pragma unroll
            for (int j = 0; j < 4; j++)
                out[(size_t)(row + j) * 2048 + col] = acc[mi][ni][j] + bb;
        }
    }
}

// ---------------------------------------------------- RMSNorm (full DIM) + RoPE
// one block per (b*S+s) row; y: 0=q, 1=k. writes bf16 (B,H,S,HD)
// Q additionally pre-scaled by 1/sqrt(HD) * log2(e) so attn softmax can use exp2.
__global__ __launch_bounds__(256) void norm_rope(
    const float* __restrict__ qf, const float* __restrict__ kf,
    const float* __restrict__ nqw, const float* __restrict__ nkw,
    const float* __restrict__ fc, const float* __restrict__ fs,
    unsigned short* __restrict__ Qr, unsigned short* __restrict__ Kr) {
    const int row = blockIdx.x;
    const int which = blockIdx.y;
    const float* in = which ? kf : qf;
    const float* wv = which ? nkw : nqw;
    unsigned short* out = which ? Kr : Qr;
    const float qs = which ? 1.0f : 0.12751744f;  // 1/sqrt(128) * log2(e) folded into Q
    const int t = threadIdx.x;
    const float* x = in + (size_t)row * 2048 + t * 8;
    float4 v0 = ((const float4*)x)[0];
    float4 v1 = ((const float4*)x)[1];
    float xv[8] = {v0.x, v0.y, v0.z, v0.w, v1.x, v1.y, v1.z, v1.w};
    float ss = 0.f;
#pragma unroll
    for (int e = 0; e < 8; e++) ss += xv[e] * xv[e];
#pragma unroll
    for (int m = 1; m < 64; m <<= 1) ss += __shfl_xor(ss, m, 64);
    __shared__ float red[4];
    if ((t & 63) == 0) red[t >> 6] = ss;
    __syncthreads();
    const float tot = red[0] + red[1] + red[2] + red[3];
    const float r = rsqrtf(tot * (1.0f / 2048.0f) + 1e-6f);
    const int s = row & 2047, b = row >> 11;
    const int d0 = t * 8, hd0 = d0 & 127, h = d0 >> 7;
    float4 c0 = ((const float4*)(fc + s * 128 + hd0))[0];
    float4 c1 = ((const float4*)(fc + s * 128 + hd0))[1];
    float4 s0 = ((const float4*)(fs + s * 128 + hd0))[0];
    float4 s1 = ((const float4*)(fs + s * 128 + hd0))[1];
    float4 w0 = ((const float4*)(wv + d0))[0];
    float4 w1 = ((const float4*)(wv + d0))[1];
    float wn[8] = {w0.x, w0.y, w0.z, w0.w, w1.x, w1.y, w1.z, w1.w};
    float xn[8];
#pragma unroll
    for (int e = 0; e < 8; e++) xn[e] = xv[e] * wn[e] * r;
    float o[8];
    // pair (2i,2i+1): cos=fc[s,2i], sin=fs[s,2i+1]
    o[0] = xn[0] * c0.x - xn[1] * s0.y;  o[1] = xn[0] * s0.y + xn[1] * c0.x;
    o[2] = xn[2] * c0.z - xn[3] * s0.w;  o[3] = xn[2] * s0.w + xn[3] * c0.z;
    o[4] = xn[4] * c1.x - xn[5] * s1.y;  o[5] = xn[4] * s1.y + xn[5] * c1.x;
    o[6] = xn[6] * c1.z - xn[7] * s1.w;  o[7] = xn[6] * s1.w + xn[7] * c1.z;
    u16x8 pk;
#pragma unroll
    for (int e = 0; e < 8; e++) pk[e] = f2bf(o[e] * qs);
    *(u16x8*)(out + ((size_t)((b * 16 + h) * 2048 + s)) * 128 + hd0) = pk;
}

// -------------------------------------------------------------- flash attn
// grid (32, 32) -> XCD-swizzled to (head, qblk); 4 waves/block, wave = 16 q rows.
// KVBLK=64, double-buffered K/V, one barrier per tile (STAGE(next) -> compute -> sync).
// K LDS [64][128] bf16, 16B segs XOR-swizzled by (row&7); V LDS [128][64] same;
// P LDS per-wave [16][64], segs swizzled by (row&7). All MFMA-operand reads conflict-free.
__global__ __launch_bounds__(256) void attn(
    const unsigned short* __restrict__ Qr, const unsigned short* __restrict__ Kr,
    const unsigned short* __restrict__ Vt, unsigned short* __restrict__ Ao) {
    __shared__ unsigned short Kl[2][64 * 128];
    __shared__ unsigned short Vl[2][128 * 64];
    __shared__ unsigned short Pl[4][16 * 64];
    const int t = threadIdx.x, w = t >> 6, l = t & 63, lr = l & 15, lk = l >> 4;
    // XCD swizzle: 4 consecutive heads per XCD -> live K/V fits that XCD's L2
    const int hwl = blockIdx.y * gridDim.x + blockIdx.x;
    const int chunk = hwl >> 3;
    const int bh = (hwl & 7) * 4 + (chunk >> 5);
    const int q0 = (chunk & 31) * 64 + w * 16;

    const unsigned short* Qp = Qr + ((size_t)bh * 2048 + q0) * 128;
    bf16x8 aq[4];
#pragma unroll
    for (int ks = 0; ks < 4; ks++)
        aq[ks] = *(const bf16x8*)(Qp + lr * 128 + ks * 32 + lk * 8);

    f32x4 accO[8];
#pragma unroll
    for (int i = 0; i < 8; i++) accO[i] = (f32x4){0.f, 0.f, 0.f, 0.f};
    float mj[4] = {-1e30f, -1e30f, -1e30f, -1e30f};
    float lj[4] = {0.f, 0.f, 0.f, 0.f};

    const unsigned short* Kb = Kr + (size_t)bh * 2048 * 128;
    const unsigned short* Vb = Vt + (size_t)bh * 128 * 2048;
    const int krl = t >> 4, ksg = (t & 15) ^ (krl & 7);   // K stage: row t>>4 (+16c), seg swz
    const int vrl = t >> 3, vsg = (t & 7) ^ (vrl & 7);    // V stage: row t>>3 (+32c), seg swz

    auto STAGE = [&](int buf, int kv0) {
        char* kd = (char*)&Kl[buf][0] + w * 1024;
        char* vd = (char*)&Vl[buf][0] + w * 1024;
#pragma unroll
        for (int c = 0; c < 4; c++)
            gload16(Kb + (size_t)(kv0 + c * 16 + krl) * 128 + ksg * 8, kd + c * 4096);
#pragma unroll
        for (int c = 0; c < 4; c++)
            gload16(Vb + (size_t)(vrl + c * 32) * 2048 + kv0 + vsg * 8, vd + c * 4096);
    };

    STAGE(0, 0);
    __syncthreads();
    int cur = 0;
    for (int it = 0; it < 32; ++it) {
        if (it < 31) STAGE(cur ^ 1, (it + 1) * 64);
        // ---- QK^T: sfr[kc][j] = S[q = lk*4+j][key = kc*16+lr]  (log2-scaled)
        f32x4 sfr[4];
        __builtin_amdgcn_s_setprio(1);
#pragma unroll
        for (int kc = 0; kc < 4; kc++) {
            f32x4 sa = (f32x4){0.f, 0.f, 0.f, 0.f};
            const int key = kc * 16 + lr;
#pragma unroll
            for (int ks = 0; ks < 4; ks++) {
                const int seg = (ks * 4 + lk) ^ (lr & 7);
                bf16x8 bk = *(const bf16x8*)((const char*)&Kl[cur][0] + key * 256 + seg * 16);
                sa = __builtin_amdgcn_mfma_f32_16x16x32_bf16(aq[ks], bk, sa, 0, 0, 0);
            }
            sfr[kc] = sa;
        }
        __builtin_amdgcn_s_setprio(0);
        // ---- online softmax in base-2
        float corr[4];
#pragma unroll
        for (int j = 0; j < 4; j++) {
            float tm = fmaxf(fmaxf(sfr[0][j], sfr[1][j]), fmaxf(sfr[2][j], sfr[3][j]));
            tm = fmaxf(tm, __shfl_xor(tm, 1, 64));
            tm = fmaxf(tm, __shfl_xor(tm, 2, 64));
            tm = fmaxf(tm, __shfl_xor(tm, 4, 64));
            tm = fmaxf(tm, __shfl_xor(tm, 8, 64));
            const float mn = fmaxf(mj[j], tm);
            corr[j] = exp2f(mj[j] - mn);
            const float p0 = exp2f(sfr[0][j] - mn);
            const float p1 = exp2f(sfr[1][j] - mn);
            const float p2 = exp2f(sfr[2][j] - mn);
            const float p3 = exp2f(sfr[3][j] - mn);
            mj[j] = mn;
            const int row = lk * 4 + j, rx = row & 7;
            char* pb = (char*)&Pl[w][0] + row * 128 + (lr & 7) * 2;
            *(unsigned short*)(pb + ((((lr >> 3) + 0) ^ rx) << 4)) = f2bf(p0);
            *(unsigned short*)(pb + ((((lr >> 3) + 2) ^ rx) << 4)) = f2bf(p1);
            *(unsigned short*)(pb + ((((lr >> 3) + 4) ^ rx) << 4)) = f2bf(p2);
            *(unsigned short*)(pb + ((((lr >> 3) + 6) ^ rx) << 4)) = f2bf(p3);
            float ps = (p0 + p1) + (p2 + p3);
            ps += __shfl_xor(ps, 1, 64);
            ps += __shfl_xor(ps, 2, 64);
            ps += __shfl_xor(ps, 4, 64);
            ps += __shfl_xor(ps, 8, 64);
            lj[j] = lj[j] * corr[j] + ps;
        }
#pragma unroll
        for (int d0 = 0; d0 < 8; d0++)
#pragma unroll
            for (int j = 0; j < 4; j++) accO[d0][j] *= corr[j];
        // ---- PV: A = P (wave-private LDS), B = V[key][d] from Vl[d][key]
        __builtin_amdgcn_s_setprio(1);
#pragma unroll
        for (int ks = 0; ks < 2; ks++) {
            const int sg = ((ks * 4 + lk) ^ (lr & 7)) << 4;
            bf16x8 ap = *(const bf16x8*)((const char*)&Pl[w][0] + lr * 128 + sg);
#pragma unroll
            for (int d0 = 0; d0 < 8; d0++) {
                const int d = d0 * 16 + lr;
                bf16x8 bv = *(const bf16x8*)((const char*)&Vl[cur][0] + d * 128 + sg);
                accO[d0] = __builtin_amdgcn_mfma_f32_16x16x32_bf16(ap, bv, accO[d0], 0, 0, 0);
            }
        }
        __builtin_amdgcn_s_setprio(0);
        __syncthreads();
        cur ^= 1;
    }
    // epilogue: Ao (B,S,H*HD) bf16
    const int b = bh >> 4, h = bh & 15;
    float inv[4];
#pragma unroll
    for (int j = 0; j < 4; j++) inv[j] = 1.0f / lj[j];
#pragma unroll
    for (int d0 = 0; d0 < 8; d0++)
#pragma unroll
        for (int j = 0; j < 4; j++) {
            const int row = q0 + lk * 4 + j;
            Ao[((size_t)(b * 2048 + row)) * 2048 + h * 128 + d0 * 16 + lr] =
                f2bf(accO[d0][j] * inv[j]);
        }
}

// ------------------------------------------------------------------ launch
extern "C" void kernel_launch(void* const* d_in, const int* in_sizes, int n_in,
                              void* d_out, int out_size, void* d_ws, size_t ws_size,
                              hipStream_t stream) {
    const float* hs  = (const float*)d_in[0];
    const float* fc  = (const float*)d_in[1];
    const float* fs  = (const float*)d_in[2];
    const float* Wq  = (const float*)d_in[3];
    const float* bq  = (const float*)d_in[4];
    const float* Wk  = (const float*)d_in[5];
    const float* bk  = (const float*)d_in[6];
    const float* Wv  = (const float*)d_in[7];
    const float* bv  = (const float*)d_in[8];
    const float* nqw = (const float*)d_in[9];
    const float* nkw = (const float*)d_in[10];
    const float* Wo  = (const float*)d_in[11];
    const float* bo  = (const float*)d_in[12];
    float* out = (float*)d_out;

    char* p = (char*)d_ws;
    unsigned short* hs16 = (unsigned short*)p; p += (size_t)8388608 * 2;
    unsigned short* Wq16 = (unsigned short*)p; p += (size_t)4194304 * 2;
    unsigned short* Wk16 = (unsigned short*)p; p += (size_t)4194304 * 2;
    unsigned short* Wv16 = (unsigned short*)p; p += (size_t)4194304 * 2;
    unsigned short* Wo16 = (unsigned short*)p; p += (size_t)4194304 * 2;
    float* qf = (float*)p;                     p += (size_t)8388608 * 4;
    float* kf = (float*)p;                     p += (size_t)8388608 * 4;
    unsigned short* Qr = (unsigned short*)p;   p += (size_t)8388608 * 2;
    unsigned short* Kr = (unsigned short*)p;   p += (size_t)8388608 * 2;
    unsigned short* Vt = (unsigned short*)p;   p += (size_t)8388608 * 2;
    unsigned short* Ao = (unsigned short*)p;   p += (size_t)8388608 * 2;
    (void)ws_size; (void)in_sizes; (void)n_in; (void)out_size;

    cvt_bf16<<<8192, 256, 0, stream>>>(hs, hs16, 2097152);
    cvt_bf16<<<4096, 256, 0, stream>>>(Wq, Wq16, 1048576);
    cvt_bf16<<<4096, 256, 0, stream>>>(Wk, Wk16, 1048576);
    cvt_bf16<<<4096, 256, 0, stream>>>(Wv, Wv16, 1048576);
    cvt_bf16<<<4096, 256, 0, stream>>>(Wo, Wo16, 1048576);

    gemm_qkv<<<dim3(16, 32, 3), 256, 0, stream>>>(hs16, Wq16, Wk16, Wv16,
                                                  bq, bk, bv, qf, kf, Vt);
    norm_rope<<<dim3(4096, 2), 256, 0, stream>>>(qf, kf, nqw, nkw, fc, fs, Qr, Kr);
    attn<<<dim3(32, 32), 256, 0, stream>>>(Qr, Kr, Vt, Ao);
    gemm_o<<<dim3(16, 32), 256, 0, stream>>>(Ao, Wo16, bo, out);
}

// Round 3
// 363.738 us; speedup vs baseline: 1.4036x; 1.2371x over previous
//
#include <hip/hip_runtime.h>
#include <stdint.h>

#define DEVI __device__ __forceinline__

typedef __attribute__((ext_vector_type(8))) short bf16x8;
typedef __attribute__((ext_vector_type(4))) float f32x4;
typedef __attribute__((ext_vector_type(16))) float f32x16;
typedef __attribute__((ext_vector_type(4))) unsigned short u16x4;
typedef __attribute__((ext_vector_type(8))) unsigned short u16x8;

// round-to-nearest-even f32 -> bf16
DEVI unsigned short f2bf(float f) {
    union { float f; unsigned u; } v; v.f = f;
    unsigned r = v.u + 0x7fffu + ((v.u >> 16) & 1u);
    return (unsigned short)(r >> 16);
}

// pack two f32 -> two bf16 in one dword (RNE), hw instruction
DEVI unsigned cvtpk(float lo, float hi) {
    unsigned r;
    asm("v_cvt_pk_bf16_f32 %0, %1, %2" : "=v"(r) : "v"(lo), "v"(hi));
    return r;
}

// async global->LDS, 16B per lane. LDS dest = wave-uniform base + lane*16.
DEVI void gload16(const void* g, void* lds) {
    __builtin_amdgcn_global_load_lds(
        (const __attribute__((address_space(1))) unsigned int*)(uintptr_t)g,
        (__attribute__((address_space(3))) unsigned int*)(unsigned int)(uintptr_t)lds,
        16, 0, 0);
}

// ---------------------------------------------------------------- convert
__global__ __launch_bounds__(256) void cvt_bf16(const float* __restrict__ in,
                                                unsigned short* __restrict__ out, int n4) {
    int i = blockIdx.x * 256 + threadIdx.x;
    if (i >= n4) return;
    float4 v = ((const float4*)in)[i];
    u16x4 pk;
    pk[0] = f2bf(v.x); pk[1] = f2bf(v.y); pk[2] = f2bf(v.z); pk[3] = f2bf(v.w);
    ((u16x4*)out)[i] = pk;
}

// ------------------------------------------------------------- GEMM core
// C[m][n] = sum_k A[m][k] * W[n][k]   (B^T layout; both row-major, K contiguous)
DEVI void gemm_core_bt(const unsigned short* A, const unsigned short* W, int K,
                       unsigned short* As, unsigned short* Bs,
                       int m0, int n0, f32x4 acc[4][4]) {
    const int t = threadIdx.x;
    const int w = t >> 6, l = t & 63, lr = l & 15, lk = l >> 4;
    const int wr = w >> 1, wc = w & 1;
    const unsigned short* a_src = A + (size_t)(m0 + (t >> 2)) * K + (t & 3) * 8;
    const unsigned short* b_src = W + (size_t)(n0 + (t >> 2)) * K + (t & 3) * 8;
    char* as_base = (char*)As + w * 1024;
    char* bs_base = (char*)Bs + w * 1024;
#pragma unroll
    for (int i = 0; i < 4; i++)
#pragma unroll
        for (int j = 0; j < 4; j++) acc[i][j] = (f32x4){0.f, 0.f, 0.f, 0.f};

    for (int k0 = 0; k0 < K; k0 += 32) {
        gload16(a_src + k0, as_base);
        gload16(a_src + (size_t)64 * K + k0, as_base + 4096);
        gload16(b_src + k0, bs_base);
        gload16(b_src + (size_t)64 * K + k0, bs_base + 4096);
        __syncthreads();
        bf16x8 af[4], bf[4];
#pragma unroll
        for (int mi = 0; mi < 4; mi++)
            af[mi] = *(const bf16x8*)((const char*)As + (wr * 64 + mi * 16 + lr) * 64 + lk * 16);
#pragma unroll
        for (int ni = 0; ni < 4; ni++)
            bf[ni] = *(const bf16x8*)((const char*)Bs + (wc * 64 + ni * 16 + lr) * 64 + lk * 16);
#pragma unroll
        for (int mi = 0; mi < 4; mi++)
#pragma unroll
            for (int ni = 0; ni < 4; ni++)
                acc[mi][ni] = __builtin_amdgcn_mfma_f32_16x16x32_bf16(af[mi], bf[ni], acc[mi][ni], 0, 0, 0);
        __syncthreads();
    }
}

// qkv: z=0 -> q (fp32), z=1 -> k (fp32), z=2 -> v (bf16, transposed to (B,H,HD,S))
__global__ __launch_bounds__(256) void gemm_qkv(
    const unsigned short* __restrict__ A,
    const unsigned short* __restrict__ Wq16, const unsigned short* __restrict__ Wk16,
    const unsigned short* __restrict__ Wv16,
    const float* __restrict__ bq, const float* __restrict__ bk, const float* __restrict__ bv,
    float* __restrict__ qf, float* __restrict__ kf, unsigned short* __restrict__ Vt) {
    __shared__ unsigned short As[128 * 32];
    __shared__ unsigned short Bs[128 * 32];
    const int t = threadIdx.x;
    const int w = t >> 6, l = t & 63, lr = l & 15, lk = l >> 4;
    const int wr = w >> 1, wc = w & 1;
    const int n0 = blockIdx.x * 128, m0 = blockIdx.y * 128;
    const int z = blockIdx.z;
    const unsigned short* W = (z == 0) ? Wq16 : (z == 1) ? Wk16 : Wv16;
    const float* bias = (z == 0) ? bq : (z == 1) ? bk : bv;

    f32x4 acc[4][4];
    gemm_core_bt(A, W, 2048, As, Bs, m0, n0, acc);

#pragma unroll
    for (int ni = 0; ni < 4; ni++) {
        const int col = n0 + wc * 64 + ni * 16 + lr;
        const float bb = bias[col];
#pragma unroll
        for (int mi = 0; mi < 4; mi++) {
            const int row = m0 + wr * 64 + mi * 16 + lk * 4;
            if (z == 2) {
                const int h = col >> 7, d = col & 127;
                const int b = row >> 11, s = row & 2047;
                u16x4 pk;
#pragma unroll
                for (int j = 0; j < 4; j++) pk[j] = f2bf(acc[mi][ni][j] + bb);
                *(u16x4*)(Vt + ((size_t)((b * 16 + h) * 128 + d)) * 2048 + s) = pk;
            } else {
                float* out = (z == 0) ? qf : kf;
#pragma unroll
                for (int j = 0; j < 4; j++)
                    out[(size_t)(row + j) * 2048 + col] = acc[mi][ni][j] + bb;
            }
        }
    }
}

__global__ __launch_bounds__(256) void gemm_o(
    const unsigned short* __restrict__ A, const unsigned short* __restrict__ W16,
    const float* __restrict__ bo, float* __restrict__ out) {
    __shared__ unsigned short As[128 * 32];
    __shared__ unsigned short Bs[128 * 32];
    const int t = threadIdx.x;
    const int w = t >> 6, l = t & 63, lr = l & 15, lk = l >> 4;
    const int wr = w >> 1, wc = w & 1;
    const int n0 = blockIdx.x * 128, m0 = blockIdx.y * 128;
    f32x4 acc[4][4];
    gemm_core_bt(A, W16, 2048, As, Bs, m0, n0, acc);
#pragma unroll
    for (int ni = 0; ni < 4; ni++) {
        const int col = n0 + wc * 64 + ni * 16 + lr;
        const float bb = bo[col];
#pragma unroll
        for (int mi = 0; mi < 4; mi++) {
            const int row = m0 + wr * 64 + mi * 16 + lk * 4;
#pragma unroll
            for (int j = 0; j < 4; j++)
                out[(size_t)(row + j) * 2048 + col] = acc[mi][ni][j] + bb;
        }
    }
}

// ---------------------------------------------------- RMSNorm (full DIM) + RoPE
// Q pre-scaled by 1/sqrt(HD)*log2(e) so attn softmax runs in base-2.
__global__ __launch_bounds__(256) void norm_rope(
    const float* __restrict__ qf, const float* __restrict__ kf,
    const float* __restrict__ nqw, const float* __restrict__ nkw,
    const float* __restrict__ fc, const float* __restrict__ fs,
    unsigned short* __restrict__ Qr, unsigned short* __restrict__ Kr) {
    const int row = blockIdx.x;
    const int which = blockIdx.y;
    const float* in = which ? kf : qf;
    const float* wv = which ? nkw : nqw;
    unsigned short* out = which ? Kr : Qr;
    const float qs = which ? 1.0f : 0.12751744f;  // 1/sqrt(128) * log2(e)
    const int t = threadIdx.x;
    const float* x = in + (size_t)row * 2048 + t * 8;
    float4 v0 = ((const float4*)x)[0];
    float4 v1 = ((const float4*)x)[1];
    float xv[8] = {v0.x, v0.y, v0.z, v0.w, v1.x, v1.y, v1.z, v1.w};
    float ss = 0.f;
#pragma unroll
    for (int e = 0; e < 8; e++) ss += xv[e] * xv[e];
#pragma unroll
    for (int m = 1; m < 64; m <<= 1) ss += __shfl_xor(ss, m, 64);
    __shared__ float red[4];
    if ((t & 63) == 0) red[t >> 6] = ss;
    __syncthreads();
    const float tot = red[0] + red[1] + red[2] + red[3];
    const float r = rsqrtf(tot * (1.0f / 2048.0f) + 1e-6f);
    const int s = row & 2047, b = row >> 11;
    const int d0 = t * 8, hd0 = d0 & 127, h = d0 >> 7;
    float4 c0 = ((const float4*)(fc + s * 128 + hd0))[0];
    float4 c1 = ((const float4*)(fc + s * 128 + hd0))[1];
    float4 s0 = ((const float4*)(fs + s * 128 + hd0))[0];
    float4 s1 = ((const float4*)(fs + s * 128 + hd0))[1];
    float4 w0 = ((const float4*)(wv + d0))[0];
    float4 w1 = ((const float4*)(wv + d0))[1];
    float wn[8] = {w0.x, w0.y, w0.z, w0.w, w1.x, w1.y, w1.z, w1.w};
    float xn[8];
#pragma unroll
    for (int e = 0; e < 8; e++) xn[e] = xv[e] * wn[e] * r;
    float o[8];
    o[0] = xn[0] * c0.x - xn[1] * s0.y;  o[1] = xn[0] * s0.y + xn[1] * c0.x;
    o[2] = xn[2] * c0.z - xn[3] * s0.w;  o[3] = xn[2] * s0.w + xn[3] * c0.z;
    o[4] = xn[4] * c1.x - xn[5] * s1.y;  o[5] = xn[4] * s1.y + xn[5] * c1.x;
    o[6] = xn[6] * c1.z - xn[7] * s1.w;  o[7] = xn[6] * s1.w + xn[7] * c1.z;
    u16x8 pk;
#pragma unroll
    for (int e = 0; e < 8; e++) pk[e] = f2bf(o[e] * qs);
    *(u16x8*)(out + ((size_t)((b * 16 + h) * 2048 + s)) * 128 + hd0) = pk;
}

// -------------------------------------------------------------- flash attn
// 8 waves x 32 q-rows (block = 256 q rows), KVBLK=64, swapped-QK 32x32x16 MFMA.
// S = mfma(K, Q) -> lane owns q=lane&31; softmax per-lane scalar (T12);
// P packed to bf16 via v_cvt_pk + shfl_xor(32) word exchange -> PV B-operand in regs.
// K LDS [64][128], V^T LDS [128][64], both 16B-seg XOR-swizzled by (row&7), dbuf.
__global__ __launch_bounds__(512, 2) void attn(
    const unsigned short* __restrict__ Qr, const unsigned short* __restrict__ Kr,
    const unsigned short* __restrict__ Vt, unsigned short* __restrict__ Ao) {
    __shared__ unsigned short Kl[2][64 * 128];
    __shared__ unsigned short Vl[2][128 * 64];
    const int t = threadIdx.x, w = t >> 6, l = t & 63;
    const int ql = l & 31, h = l >> 5;
    // XCD swizzle: 4 heads per XCD (4MB K/V working set = one XCD L2)
    const int bid = blockIdx.x;
    const int xcd = bid & 7, idx = bid >> 3;
    const int bh = xcd * 4 + (idx >> 3);
    const int q0 = (idx & 7) * 256 + w * 32;
    const int b = bh >> 4, head = bh & 15;

    // Q fragments (B operand): n=q=lane&31, k=h*8+e per 16-k chunk
    const unsigned short* Qp = Qr + ((size_t)bh * 2048 + q0) * 128;
    bf16x8 qf[8];
#pragma unroll
    for (int c8 = 0; c8 < 8; c8++)
        qf[c8] = *(const bf16x8*)(Qp + ql * 128 + c8 * 16 + h * 8);

    f32x16 accO[4];
#pragma unroll
    for (int dt = 0; dt < 4; dt++)
#pragma unroll
        for (int r = 0; r < 16; r++) accO[dt][r] = 0.f;
    float mj = -1e30f, ljp = 0.f;

    const unsigned short* Kb = Kr + (size_t)bh * 2048 * 128;
    const unsigned short* Vb = Vt + (size_t)bh * 128 * 2048;
    // staging: pre-swizzled global source, linear LDS dest (gload16)
    const int krow = t >> 4, kseg = (t & 15) ^ (krow & 7);
    const int vrow = t >> 3, vseg = (t & 7) ^ (vrow & 7);

    auto STAGE = [&](int buf, int kv0) {
        char* kd = (char*)&Kl[buf][0] + w * 1024;
        char* vd = (char*)&Vl[buf][0] + w * 1024;
        gload16(Kb + (size_t)(kv0 + krow) * 128 + kseg * 8, kd);
        gload16(Kb + (size_t)(kv0 + 32 + krow) * 128 + kseg * 8, kd + 8192);
        gload16(Vb + (size_t)vrow * 2048 + kv0 + vseg * 8, vd);
        gload16(Vb + (size_t)(64 + vrow) * 2048 + kv0 + vseg * 8, vd + 8192);
    };

    const int qx = ql & 7;          // row-XOR for swizzled reads
    STAGE(0, 0);
    __syncthreads();
    int cur = 0;
    for (int it = 0; it < 32; ++it) {
        if (it < 31) STAGE(cur ^ 1, (it + 1) * 64);
        // ---- QK^T (swapped): S[key][q], two 32-key sets
        f32x16 S0, S1;
#pragma unroll
        for (int r = 0; r < 16; r++) { S0[r] = 0.f; S1[r] = 0.f; }
        __builtin_amdgcn_s_setprio(1);
#pragma unroll
        for (int c8 = 0; c8 < 8; c8++) {
            const int sg = ((c8 * 2 + h) ^ qx) << 4;
            bf16x8 k0 = *(const bf16x8*)((const char*)&Kl[cur][0] + ql * 256 + sg);
            bf16x8 k1 = *(const bf16x8*)((const char*)&Kl[cur][0] + (32 + ql) * 256 + sg);
            S0 = __builtin_amdgcn_mfma_f32_32x32x16_bf16(k0, qf[c8], S0, 0, 0, 0);
            S1 = __builtin_amdgcn_mfma_f32_32x32x16_bf16(k1, qf[c8], S1, 0, 0, 0);
        }
        __builtin_amdgcn_s_setprio(0);
        // ---- per-lane online softmax (keys split lane<->lane^32)
        float mloc = S0[0];
#pragma unroll
        for (int r = 1; r < 16; r++) mloc = fmaxf(mloc, S0[r]);
#pragma unroll
        for (int r = 0; r < 16; r++) mloc = fmaxf(mloc, S1[r]);
        const float mx = fmaxf(mloc, __shfl_xor(mloc, 32, 64));
        if (!__all(mx <= mj + 8.0f)) {          // T13 defer-max, THR=8
            const float mn = fmaxf(mj, mx);
            const float corr = exp2f(mj - mn);
            mj = mn;
            ljp *= corr;
#pragma unroll
            for (int dt = 0; dt < 4; dt++)
#pragma unroll
                for (int r = 0; r < 16; r++) accO[dt][r] *= corr;
        }
        unsigned W[16];
        float lsum = 0.f;
#pragma unroll
        for (int i = 0; i < 8; i++) {
            const float pa = exp2f(S0[2 * i] - mj);
            const float pb = exp2f(S0[2 * i + 1] - mj);
            W[i] = cvtpk(pa, pb);
            lsum += pa + pb;
        }
#pragma unroll
        for (int i = 0; i < 8; i++) {
            const float pa = exp2f(S1[2 * i] - mj);
            const float pb = exp2f(S1[2 * i + 1] - mj);
            W[8 + i] = cvtpk(pa, pb);
            lsum += pa + pb;
        }
        ljp += lsum;
        // ---- PV: per key-set, exchange packed words across halves, 2 chunks of K=16
#pragma unroll
        for (int c = 0; c < 2; c++) {
            unsigned X[8];
#pragma unroll
            for (int i = 0; i < 8; i++)
                X[i] = (unsigned)__shfl_xor((int)W[c * 8 + i], 32, 64);
            union U { unsigned u[4]; bf16x8 v; };
            U F, G;
            F.u[0] = h ? X[2] : W[c * 8 + 0];
            F.u[1] = h ? X[3] : W[c * 8 + 1];
            F.u[2] = h ? W[c * 8 + 2] : X[0];
            F.u[3] = h ? W[c * 8 + 3] : X[1];
            G.u[0] = h ? X[6] : W[c * 8 + 4];
            G.u[1] = h ? X[7] : W[c * 8 + 5];
            G.u[2] = h ? W[c * 8 + 6] : X[4];
            G.u[3] = h ? W[c * 8 + 7] : X[5];
            __builtin_amdgcn_s_setprio(1);
#pragma unroll
            for (int dt = 0; dt < 4; dt++) {
                const int sg = (((2 * c) * 2 + h) ^ qx) << 4;
                bf16x8 vf = *(const bf16x8*)((const char*)&Vl[cur][0] + (dt * 32 + ql) * 128 + sg);
                accO[dt] = __builtin_amdgcn_mfma_f32_32x32x16_bf16(vf, F.v, accO[dt], 0, 0, 0);
            }
#pragma unroll
            for (int dt = 0; dt < 4; dt++) {
                const int sg = (((2 * c + 1) * 2 + h) ^ qx) << 4;
                bf16x8 vf = *(const bf16x8*)((const char*)&Vl[cur][0] + (dt * 32 + ql) * 128 + sg);
                accO[dt] = __builtin_amdgcn_mfma_f32_32x32x16_bf16(vf, G.v, accO[dt], 0, 0, 0);
            }
            __builtin_amdgcn_s_setprio(0);
        }
        __syncthreads();
        cur ^= 1;
    }
    // ---- epilogue: O^T[d][q] per lane; Ao (B,S,H*HD) bf16, paired dword stores
    const float lj = ljp + __shfl_xor(ljp, 32, 64);
    const float inv = 1.0f / lj;
    unsigned short* ob = Ao + ((size_t)(b * 2048 + q0 + ql)) * 2048 + head * 128;
#pragma unroll
    for (int dt = 0; dt < 4; dt++)
#pragma unroll
        for (int i = 0; i < 8; i++) {
            const float a = accO[dt][2 * i] * inv;
            const float c = accO[dt][2 * i + 1] * inv;
            const int d = dt * 32 + ((2 * i) & 3) + 8 * (i >> 1) + 4 * h;
            *(unsigned*)(ob + d) = cvtpk(a, c);
        }
}

// ------------------------------------------------------------------ launch
extern "C" void kernel_launch(void* const* d_in, const int* in_sizes, int n_in,
                              void* d_out, int out_size, void* d_ws, size_t ws_size,
                              hipStream_t stream) {
    const float* hs  = (const float*)d_in[0];
    const float* fc  = (const float*)d_in[1];
    const float* fs  = (const float*)d_in[2];
    const float* Wq  = (const float*)d_in[3];
    const float* bq  = (const float*)d_in[4];
    const float* Wk  = (const float*)d_in[5];
    const float* bk  = (const float*)d_in[6];
    const float* Wv  = (const float*)d_in[7];
    const float* bv  = (const float*)d_in[8];
    const float* nqw = (const float*)d_in[9];
    const float* nkw = (const float*)d_in[10];
    const float* Wo  = (const float*)d_in[11];
    const float* bo  = (const float*)d_in[12];
    float* out = (float*)d_out;

    char* p = (char*)d_ws;
    unsigned short* hs16 = (unsigned short*)p; p += (size_t)8388608 * 2;
    unsigned short* Wq16 = (unsigned short*)p; p += (size_t)4194304 * 2;
    unsigned short* Wk16 = (unsigned short*)p; p += (size_t)4194304 * 2;
    unsigned short* Wv16 = (unsigned short*)p; p += (size_t)4194304 * 2;
    unsigned short* Wo16 = (unsigned short*)p; p += (size_t)4194304 * 2;
    float* qf = (float*)p;                     p += (size_t)8388608 * 4;
    float* kf = (float*)p;                     p += (size_t)8388608 * 4;
    unsigned short* Qr = (unsigned short*)p;   p += (size_t)8388608 * 2;
    unsigned short* Kr = (unsigned short*)p;   p += (size_t)8388608 * 2;
    unsigned short* Vt = (unsigned short*)p;   p += (size_t)8388608 * 2;
    unsigned short* Ao = (unsigned short*)p;   p += (size_t)8388608 * 2;
    (void)ws_size; (void)in_sizes; (void)n_in; (void)out_size;

    cvt_bf16<<<8192, 256, 0, stream>>>(hs, hs16, 2097152);
    cvt_bf16<<<4096, 256, 0, stream>>>(Wq, Wq16, 1048576);
    cvt_bf16<<<4096, 256, 0, stream>>>(Wk, Wk16, 1048576);
    cvt_bf16<<<4096, 256, 0, stream>>>(Wv, Wv16, 1048576);
    cvt_bf16<<<4096, 256, 0, stream>>>(Wo, Wo16, 1048576);

    gemm_qkv<<<dim3(16, 32, 3), 256, 0, stream>>>(hs16, Wq16, Wk16, Wv16,
                                                  bq, bk, bv, qf, kf, Vt);
    norm_rope<<<dim3(4096, 2), 256, 0, stream>>>(qf, kf, nqw, nkw, fc, fs, Qr, Kr);
    attn<<<256, 512, 0, stream>>>(Qr, Kr, Vt, Ao);
    gemm_o<<<dim3(16, 32), 256, 0, stream>>>(Ao, Wo16, bo, out);
}

// Round 4
// 333.992 us; speedup vs baseline: 1.5286x; 1.0891x over previous
//
#include <hip/hip_runtime.h>
#include <stdint.h>

#define DEVI __device__ __forceinline__

typedef __attribute__((ext_vector_type(8))) short bf16x8;
typedef __attribute__((ext_vector_type(4))) float f32x4;
typedef __attribute__((ext_vector_type(16))) float f32x16;
typedef __attribute__((ext_vector_type(4))) unsigned short u16x4;
typedef __attribute__((ext_vector_type(8))) unsigned short u16x8;

// round-to-nearest-even f32 -> bf16
DEVI unsigned short f2bf(float f) {
    union { float f; unsigned u; } v; v.f = f;
    unsigned r = v.u + 0x7fffu + ((v.u >> 16) & 1u);
    return (unsigned short)(r >> 16);
}

// pack two f32 -> two bf16 in one dword (RNE), hw instruction
DEVI unsigned cvtpk(float lo, float hi) {
    unsigned r;
    asm("v_cvt_pk_bf16_f32 %0, %1, %2" : "=v"(r) : "v"(lo), "v"(hi));
    return r;
}

// async global->LDS, 16B per lane. LDS dest = wave-uniform base + lane*16.
DEVI void gload16(const void* g, void* lds) {
    __builtin_amdgcn_global_load_lds(
        (const __attribute__((address_space(1))) unsigned int*)(uintptr_t)g,
        (__attribute__((address_space(3))) unsigned int*)(unsigned int)(uintptr_t)lds,
        16, 0, 0);
}

// ---------------------------------------------------------------- convert
__global__ __launch_bounds__(256) void cvt_bf16(const float* __restrict__ in,
                                                unsigned short* __restrict__ out, int n4) {
    int i = blockIdx.x * 256 + threadIdx.x;
    if (i >= n4) return;
    float4 v = ((const float4*)in)[i];
    u16x4 pk;
    pk[0] = f2bf(v.x); pk[1] = f2bf(v.y); pk[2] = f2bf(v.z); pk[3] = f2bf(v.w);
    ((u16x4*)out)[i] = pk;
}

// ------------------------------------------------------- pipelined GEMM core
// C[m][n] = sum_k A[m][k] * W[n][k], tile 128x256, BK=64, K=2048.
// 8 waves (2x4), per-wave 64x64 out = 2x2 frags of mfma_32x32x16_bf16.
// 3 LDS buffers, stage lookahead = 2 K-tiles; per-tile counted vmcnt(6);
// 2 phases per tile {ds_read, stage-issue, bar, MFMA, bar}; setprio around MFMA.
// LDS rows = 128B = 8 x 16B segs, XOR-swizzled seg ^= (row&7) (pre-swizzled source).
DEVI void gemm_pipe_core(const unsigned short* __restrict__ A,
                         const unsigned short* __restrict__ Wt,
                         int m0, int n0, unsigned short* Al, unsigned short* Bl,
                         f32x16 acc[2][2]) {
    constexpr int K = 2048, NT = 32;
    const int t = threadIdx.x;
    const int w = t >> 6, l = t & 63;
    const int q = l & 31, h = l >> 5;
    const int wr = w >> 2, wc = w & 3;
    const int qx = q & 7;
    const int srow = t >> 3, sseg = (t & 7) ^ (srow & 7);
    const unsigned short* aS = A + (size_t)(m0 + srow) * K + sseg * 8;
    const unsigned short* bS = Wt + (size_t)(n0 + srow) * K + sseg * 8;

#pragma unroll
    for (int mi = 0; mi < 2; mi++)
#pragma unroll
        for (int ni = 0; ni < 2; ni++)
#pragma unroll
            for (int r = 0; r < 16; r++) acc[mi][ni][r] = 0.f;

    auto STAGE_P1 = [&](int rb, int kt) {  // B rows 0-127, A rows 0-63
        const int k0 = kt * 64;
        char* bd = (char*)Bl + rb * 32768 + w * 1024;
        char* ad = (char*)Al + rb * 16384 + w * 1024;
        gload16(bS + k0, bd);
        gload16(bS + (size_t)64 * K + k0, bd + 8192);
        gload16(aS + k0, ad);
    };
    auto STAGE_P2 = [&](int rb, int kt) {  // B rows 128-255, A rows 64-127
        const int k0 = kt * 64;
        char* bd = (char*)Bl + rb * 32768 + w * 1024;
        char* ad = (char*)Al + rb * 16384 + w * 1024;
        gload16(bS + (size_t)128 * K + k0, bd + 16384);
        gload16(bS + (size_t)192 * K + k0, bd + 24576);
        gload16(aS + (size_t)64 * K + k0, ad + 8192);
    };

    STAGE_P1(0, 0); STAGE_P2(0, 0);
    STAGE_P1(1, 1); STAGE_P2(1, 1);
    asm volatile("s_waitcnt vmcnt(6)" ::: "memory");
    __builtin_amdgcn_s_barrier();

    int rb = 0;
    for (int kt = 0; kt < NT; ++kt) {
        const int r2 = (rb >= 1) ? rb - 1 : 2;   // (rb+2)%3
        const char* Ab = (const char*)Al + rb * 16384;
        const char* Bb = (const char*)Bl + rb * 32768;
        // ---- phase 1: read A (both mi) + B(ni=0); stage half of tile kt+2
        bf16x8 a[2][4], b[4];
#pragma unroll
        for (int mi = 0; mi < 2; mi++)
#pragma unroll
            for (int ks = 0; ks < 4; ks++)
                a[mi][ks] = *(const bf16x8*)(Ab + (wr * 64 + mi * 32 + q) * 128 +
                                             (((ks * 2 + h) ^ qx) << 4));
#pragma unroll
        for (int ks = 0; ks < 4; ks++)
            b[ks] = *(const bf16x8*)(Bb + (wc * 64 + q) * 128 +
                                     (((ks * 2 + h) ^ qx) << 4));
        if (kt + 2 < NT) STAGE_P1(r2, kt + 2);
        __builtin_amdgcn_s_barrier();
        __builtin_amdgcn_s_setprio(1);
#pragma unroll
        for (int ks = 0; ks < 4; ks++) {
            acc[0][0] = __builtin_amdgcn_mfma_f32_32x32x16_bf16(a[0][ks], b[ks], acc[0][0], 0, 0, 0);
            acc[1][0] = __builtin_amdgcn_mfma_f32_32x32x16_bf16(a[1][ks], b[ks], acc[1][0], 0, 0, 0);
        }
        __builtin_amdgcn_s_setprio(0);
        __builtin_amdgcn_s_barrier();
        // ---- phase 2: read B(ni=1); stage other half of tile kt+2
#pragma unroll
        for (int ks = 0; ks < 4; ks++)
            b[ks] = *(const bf16x8*)(Bb + (wc * 64 + 32 + q) * 128 +
                                     (((ks * 2 + h) ^ qx) << 4));
        if (kt + 2 < NT) STAGE_P2(r2, kt + 2);
        __builtin_amdgcn_s_barrier();
        __builtin_amdgcn_s_setprio(1);
#pragma unroll
        for (int ks = 0; ks < 4; ks++) {
            acc[0][1] = __builtin_amdgcn_mfma_f32_32x32x16_bf16(a[0][ks], b[ks], acc[0][1], 0, 0, 0);
            acc[1][1] = __builtin_amdgcn_mfma_f32_32x32x16_bf16(a[1][ks], b[ks], acc[1][1], 0, 0, 0);
        }
        __builtin_amdgcn_s_setprio(0);
        if (kt + 2 < NT) asm volatile("s_waitcnt vmcnt(6)" ::: "memory");
        else             asm volatile("s_waitcnt vmcnt(0)" ::: "memory");
        __builtin_amdgcn_s_barrier();
        rb = (rb + 1 >= 3) ? 0 : rb + 1;
    }
}

// qkv: z=0 -> q (fp32), z=1 -> k (fp32), z=2 -> v (bf16, transposed to (B,H,HD,S))
__global__ __launch_bounds__(512, 2) void gemm_qkv(
    const unsigned short* __restrict__ A,
    const unsigned short* __restrict__ Wq16, const unsigned short* __restrict__ Wk16,
    const unsigned short* __restrict__ Wv16,
    const float* __restrict__ bq, const float* __restrict__ bk, const float* __restrict__ bv,
    float* __restrict__ qf, float* __restrict__ kf, unsigned short* __restrict__ Vt) {
    __shared__ unsigned short Al[3 * 128 * 64];
    __shared__ unsigned short Bl[3 * 256 * 64];
    const int bid = blockIdx.x;
    // XCD partition by n-tile: W panels (3MB) stay L2-resident per XCD
    const int nt = bid & 7, rem = bid >> 3;
    const int mt = rem / 3, z = rem % 3;
    const int m0 = mt * 128, n0 = nt * 256;
    const unsigned short* W = (z == 0) ? Wq16 : (z == 1) ? Wk16 : Wv16;
    const float* bias = (z == 0) ? bq : (z == 1) ? bk : bv;

    f32x16 acc[2][2];
    gemm_pipe_core(A, W, m0, n0, Al, Bl, acc);

    const int t = threadIdx.x, w = t >> 6, l = t & 63;
    const int q = l & 31, h = l >> 5;
    const int wr = w >> 2, wc = w & 3;
#pragma unroll
    for (int mi = 0; mi < 2; mi++)
#pragma unroll
        for (int ni = 0; ni < 2; ni++) {
            const int col = n0 + wc * 64 + ni * 32 + q;
            const float bb = bias[col];
            if (z == 2) {
                const int hh = col >> 7, d = col & 127;
#pragma unroll
                for (int rq = 0; rq < 4; rq++) {
                    const int row = m0 + wr * 64 + mi * 32 + 8 * rq + 4 * h;
                    const int b = row >> 11, s = row & 2047;
                    u16x4 pk;
#pragma unroll
                    for (int j = 0; j < 4; j++) pk[j] = f2bf(acc[mi][ni][rq * 4 + j] + bb);
                    *(u16x4*)(Vt + ((size_t)((b * 16 + hh) * 128 + d)) * 2048 + s) = pk;
                }
            } else {
                float* out = (z == 0) ? qf : kf;
#pragma unroll
                for (int rq = 0; rq < 4; rq++) {
                    const int row = m0 + wr * 64 + mi * 32 + 8 * rq + 4 * h;
#pragma unroll
                    for (int j = 0; j < 4; j++)
                        out[(size_t)(row + j) * 2048 + col] = acc[mi][ni][rq * 4 + j] + bb;
                }
            }
        }
}

__global__ __launch_bounds__(512, 2) void gemm_o(
    const unsigned short* __restrict__ A, const unsigned short* __restrict__ W16,
    const float* __restrict__ bo, float* __restrict__ out) {
    __shared__ unsigned short Al[3 * 128 * 64];
    __shared__ unsigned short Bl[3 * 256 * 64];
    const int bid = blockIdx.x;
    const int swz = (bid & 7) * 32 + (bid >> 3);     // XCD chunk: 4 m-tiles x all n
    const int mt = swz >> 3, nt = swz & 7;
    const int m0 = mt * 128, n0 = nt * 256;

    f32x16 acc[2][2];
    gemm_pipe_core(A, W16, m0, n0, Al, Bl, acc);

    const int t = threadIdx.x, w = t >> 6, l = t & 63;
    const int q = l & 31, h = l >> 5;
    const int wr = w >> 2, wc = w & 3;
#pragma unroll
    for (int mi = 0; mi < 2; mi++)
#pragma unroll
        for (int ni = 0; ni < 2; ni++) {
            const int col = n0 + wc * 64 + ni * 32 + q;
            const float bb = bo[col];
#pragma unroll
            for (int rq = 0; rq < 4; rq++) {
                const int row = m0 + wr * 64 + mi * 32 + 8 * rq + 4 * h;
#pragma unroll
                for (int j = 0; j < 4; j++)
                    out[(size_t)(row + j) * 2048 + col] = acc[mi][ni][rq * 4 + j] + bb;
            }
        }
}

// ---------------------------------------------------- RMSNorm (full DIM) + RoPE
// Q pre-scaled by 1/sqrt(HD)*log2(e) so attn softmax runs in base-2.
__global__ __launch_bounds__(256) void norm_rope(
    const float* __restrict__ qf, const float* __restrict__ kf,
    const float* __restrict__ nqw, const float* __restrict__ nkw,
    const float* __restrict__ fc, const float* __restrict__ fs,
    unsigned short* __restrict__ Qr, unsigned short* __restrict__ Kr) {
    const int row = blockIdx.x;
    const int which = blockIdx.y;
    const float* in = which ? kf : qf;
    const float* wv = which ? nkw : nqw;
    unsigned short* out = which ? Kr : Qr;
    const float qs = which ? 1.0f : 0.12751744f;  // 1/sqrt(128) * log2(e)
    const int t = threadIdx.x;
    const float* x = in + (size_t)row * 2048 + t * 8;
    float4 v0 = ((const float4*)x)[0];
    float4 v1 = ((const float4*)x)[1];
    float xv[8] = {v0.x, v0.y, v0.z, v0.w, v1.x, v1.y, v1.z, v1.w};
    float ss = 0.f;
#pragma unroll
    for (int e = 0; e < 8; e++) ss += xv[e] * xv[e];
#pragma unroll
    for (int m = 1; m < 64; m <<= 1) ss += __shfl_xor(ss, m, 64);
    __shared__ float red[4];
    if ((t & 63) == 0) red[t >> 6] = ss;
    __syncthreads();
    const float tot = red[0] + red[1] + red[2] + red[3];
    const float r = rsqrtf(tot * (1.0f / 2048.0f) + 1e-6f);
    const int s = row & 2047, b = row >> 11;
    const int d0 = t * 8, hd0 = d0 & 127, h = d0 >> 7;
    float4 c0 = ((const float4*)(fc + s * 128 + hd0))[0];
    float4 c1 = ((const float4*)(fc + s * 128 + hd0))[1];
    float4 s0 = ((const float4*)(fs + s * 128 + hd0))[0];
    float4 s1 = ((const float4*)(fs + s * 128 + hd0))[1];
    float4 w0 = ((const float4*)(wv + d0))[0];
    float4 w1 = ((const float4*)(wv + d0))[1];
    float wn[8] = {w0.x, w0.y, w0.z, w0.w, w1.x, w1.y, w1.z, w1.w};
    float xn[8];
#pragma unroll
    for (int e = 0; e < 8; e++) xn[e] = xv[e] * wn[e] * r;
    float o[8];
    o[0] = xn[0] * c0.x - xn[1] * s0.y;  o[1] = xn[0] * s0.y + xn[1] * c0.x;
    o[2] = xn[2] * c0.z - xn[3] * s0.w;  o[3] = xn[2] * s0.w + xn[3] * c0.z;
    o[4] = xn[4] * c1.x - xn[5] * s1.y;  o[5] = xn[4] * s1.y + xn[5] * c1.x;
    o[6] = xn[6] * c1.z - xn[7] * s1.w;  o[7] = xn[6] * s1.w + xn[7] * c1.z;
    u16x8 pk;
#pragma unroll
    for (int e = 0; e < 8; e++) pk[e] = f2bf(o[e] * qs);
    *(u16x8*)(out + ((size_t)((b * 16 + h) * 2048 + s)) * 128 + hd0) = pk;
}

// -------------------------------------------------------------- flash attn
// 8 waves x 32 q-rows (block = 256 q rows), KVBLK=64, swapped-QK 32x32x16 MFMA.
__global__ __launch_bounds__(512, 2) void attn(
    const unsigned short* __restrict__ Qr, const unsigned short* __restrict__ Kr,
    const unsigned short* __restrict__ Vt, unsigned short* __restrict__ Ao) {
    __shared__ unsigned short Kl[2][64 * 128];
    __shared__ unsigned short Vl[2][128 * 64];
    const int t = threadIdx.x, w = t >> 6, l = t & 63;
    const int ql = l & 31, h = l >> 5;
    const int bid = blockIdx.x;
    const int xcd = bid & 7, idx = bid >> 3;
    const int bh = xcd * 4 + (idx >> 3);
    const int q0 = (idx & 7) * 256 + w * 32;
    const int b = bh >> 4, head = bh & 15;

    const unsigned short* Qp = Qr + ((size_t)bh * 2048 + q0) * 128;
    bf16x8 qf[8];
#pragma unroll
    for (int c8 = 0; c8 < 8; c8++)
        qf[c8] = *(const bf16x8*)(Qp + ql * 128 + c8 * 16 + h * 8);

    f32x16 accO[4];
#pragma unroll
    for (int dt = 0; dt < 4; dt++)
#pragma unroll
        for (int r = 0; r < 16; r++) accO[dt][r] = 0.f;
    float mj = -1e30f, ljp = 0.f;

    const unsigned short* Kb = Kr + (size_t)bh * 2048 * 128;
    const unsigned short* Vb = Vt + (size_t)bh * 128 * 2048;
    const int krow = t >> 4, kseg = (t & 15) ^ (krow & 7);
    const int vrow = t >> 3, vseg = (t & 7) ^ (vrow & 7);

    auto STAGE = [&](int buf, int kv0) {
        char* kd = (char*)&Kl[buf][0] + w * 1024;
        char* vd = (char*)&Vl[buf][0] + w * 1024;
        gload16(Kb + (size_t)(kv0 + krow) * 128 + kseg * 8, kd);
        gload16(Kb + (size_t)(kv0 + 32 + krow) * 128 + kseg * 8, kd + 8192);
        gload16(Vb + (size_t)vrow * 2048 + kv0 + vseg * 8, vd);
        gload16(Vb + (size_t)(64 + vrow) * 2048 + kv0 + vseg * 8, vd + 8192);
    };

    const int qx = ql & 7;
    STAGE(0, 0);
    __syncthreads();
    int cur = 0;
    for (int it = 0; it < 32; ++it) {
        if (it < 31) STAGE(cur ^ 1, (it + 1) * 64);
        f32x16 S0, S1;
#pragma unroll
        for (int r = 0; r < 16; r++) { S0[r] = 0.f; S1[r] = 0.f; }
        __builtin_amdgcn_s_setprio(1);
#pragma unroll
        for (int c8 = 0; c8 < 8; c8++) {
            const int sg = ((c8 * 2 + h) ^ qx) << 4;
            bf16x8 k0 = *(const bf16x8*)((const char*)&Kl[cur][0] + ql * 256 + sg);
            bf16x8 k1 = *(const bf16x8*)((const char*)&Kl[cur][0] + (32 + ql) * 256 + sg);
            S0 = __builtin_amdgcn_mfma_f32_32x32x16_bf16(k0, qf[c8], S0, 0, 0, 0);
            S1 = __builtin_amdgcn_mfma_f32_32x32x16_bf16(k1, qf[c8], S1, 0, 0, 0);
        }
        __builtin_amdgcn_s_setprio(0);
        float mloc = S0[0];
#pragma unroll
        for (int r = 1; r < 16; r++) mloc = fmaxf(mloc, S0[r]);
#pragma unroll
        for (int r = 0; r < 16; r++) mloc = fmaxf(mloc, S1[r]);
        const float mx = fmaxf(mloc, __shfl_xor(mloc, 32, 64));
        if (!__all(mx <= mj + 8.0f)) {
            const float mn = fmaxf(mj, mx);
            const float corr = exp2f(mj - mn);
            mj = mn;
            ljp *= corr;
#pragma unroll
            for (int dt = 0; dt < 4; dt++)
#pragma unroll
                for (int r = 0; r < 16; r++) accO[dt][r] *= corr;
        }
        unsigned W[16];
        float lsum = 0.f;
#pragma unroll
        for (int i = 0; i < 8; i++) {
            const float pa = exp2f(S0[2 * i] - mj);
            const float pb = exp2f(S0[2 * i + 1] - mj);
            W[i] = cvtpk(pa, pb);
            lsum += pa + pb;
        }
#pragma unroll
        for (int i = 0; i < 8; i++) {
            const float pa = exp2f(S1[2 * i] - mj);
            const float pb = exp2f(S1[2 * i + 1] - mj);
            W[8 + i] = cvtpk(pa, pb);
            lsum += pa + pb;
        }
        ljp += lsum;
#pragma unroll
        for (int c = 0; c < 2; c++) {
            unsigned X[8];
#pragma unroll
            for (int i = 0; i < 8; i++)
                X[i] = (unsigned)__shfl_xor((int)W[c * 8 + i], 32, 64);
            union U { unsigned u[4]; bf16x8 v; };
            U F, G;
            F.u[0] = h ? X[2] : W[c * 8 + 0];
            F.u[1] = h ? X[3] : W[c * 8 + 1];
            F.u[2] = h ? W[c * 8 + 2] : X[0];
            F.u[3] = h ? W[c * 8 + 3] : X[1];
            G.u[0] = h ? X[6] : W[c * 8 + 4];
            G.u[1] = h ? X[7] : W[c * 8 + 5];
            G.u[2] = h ? W[c * 8 + 6] : X[4];
            G.u[3] = h ? W[c * 8 + 7] : X[5];
            __builtin_amdgcn_s_setprio(1);
#pragma unroll
            for (int dt = 0; dt < 4; dt++) {
                const int sg = (((2 * c) * 2 + h) ^ qx) << 4;
                bf16x8 vf = *(const bf16x8*)((const char*)&Vl[cur][0] + (dt * 32 + ql) * 128 + sg);
                accO[dt] = __builtin_amdgcn_mfma_f32_32x32x16_bf16(vf, F.v, accO[dt], 0, 0, 0);
            }
#pragma unroll
            for (int dt = 0; dt < 4; dt++) {
                const int sg = (((2 * c + 1) * 2 + h) ^ qx) << 4;
                bf16x8 vf = *(const bf16x8*)((const char*)&Vl[cur][0] + (dt * 32 + ql) * 128 + sg);
                accO[dt] = __builtin_amdgcn_mfma_f32_32x32x16_bf16(vf, G.v, accO[dt], 0, 0, 0);
            }
            __builtin_amdgcn_s_setprio(0);
        }
        __syncthreads();
        cur ^= 1;
    }
    const float lj = ljp + __shfl_xor(ljp, 32, 64);
    const float inv = 1.0f / lj;
    unsigned short* ob = Ao + ((size_t)(b * 2048 + q0 + ql)) * 2048 + head * 128;
#pragma unroll
    for (int dt = 0; dt < 4; dt++)
#pragma unroll
        for (int i = 0; i < 8; i++) {
            const float a = accO[dt][2 * i] * inv;
            const float c = accO[dt][2 * i + 1] * inv;
            const int d = dt * 32 + ((2 * i) & 3) + 8 * (i >> 1) + 4 * h;
            *(unsigned*)(ob + d) = cvtpk(a, c);
        }
}

// ------------------------------------------------------------------ launch
extern "C" void kernel_launch(void* const* d_in, const int* in_sizes, int n_in,
                              void* d_out, int out_size, void* d_ws, size_t ws_size,
                              hipStream_t stream) {
    const float* hs  = (const float*)d_in[0];
    const float* fc  = (const float*)d_in[1];
    const float* fs  = (const float*)d_in[2];
    const float* Wq  = (const float*)d_in[3];
    const float* bq  = (const float*)d_in[4];
    const float* Wk  = (const float*)d_in[5];
    const float* bk  = (const float*)d_in[6];
    const float* Wv  = (const float*)d_in[7];
    const float* bv  = (const float*)d_in[8];
    const float* nqw = (const float*)d_in[9];
    const float* nkw = (const float*)d_in[10];
    const float* Wo  = (const float*)d_in[11];
    const float* bo  = (const float*)d_in[12];
    float* out = (float*)d_out;

    char* p = (char*)d_ws;
    unsigned short* hs16 = (unsigned short*)p; p += (size_t)8388608 * 2;
    unsigned short* Wq16 = (unsigned short*)p; p += (size_t)4194304 * 2;
    unsigned short* Wk16 = (unsigned short*)p; p += (size_t)4194304 * 2;
    unsigned short* Wv16 = (unsigned short*)p; p += (size_t)4194304 * 2;
    unsigned short* Wo16 = (unsigned short*)p; p += (size_t)4194304 * 2;
    float* qf = (float*)p;                     p += (size_t)8388608 * 4;
    float* kf = (float*)p;                     p += (size_t)8388608 * 4;
    unsigned short* Qr = (unsigned short*)p;   p += (size_t)8388608 * 2;
    unsigned short* Kr = (unsigned short*)p;   p += (size_t)8388608 * 2;
    unsigned short* Vt = (unsigned short*)p;   p += (size_t)8388608 * 2;
    unsigned short* Ao = (unsigned short*)p;   p += (size_t)8388608 * 2;
    (void)ws_size; (void)in_sizes; (void)n_in; (void)out_size;

    cvt_bf16<<<8192, 256, 0, stream>>>(hs, hs16, 2097152);
    cvt_bf16<<<4096, 256, 0, stream>>>(Wq, Wq16, 1048576);
    cvt_bf16<<<4096, 256, 0, stream>>>(Wk, Wk16, 1048576);
    cvt_bf16<<<4096, 256, 0, stream>>>(Wv, Wv16, 1048576);
    cvt_bf16<<<4096, 256, 0, stream>>>(Wo, Wo16, 1048576);

    gemm_qkv<<<768, 512, 0, stream>>>(hs16, Wq16, Wk16, Wv16,
                                      bq, bk, bv, qf, kf, Vt);
    norm_rope<<<dim3(4096, 2), 256, 0, stream>>>(qf, kf, nqw, nkw, fc, fs, Qr, Kr);
    attn<<<256, 512, 0, stream>>>(Qr, Kr, Vt, Ao);
    gemm_o<<<256, 512, 0, stream>>>(Ao, Wo16, bo, out);
}

// Round 5
// 315.159 us; speedup vs baseline: 1.6200x; 1.0598x over previous
//
#include <hip/hip_runtime.h>
#include <stdint.h>

#define DEVI __device__ __forceinline__

typedef __attribute__((ext_vector_type(8))) short bf16x8;
typedef __attribute__((ext_vector_type(4))) float f32x4;
typedef __attribute__((ext_vector_type(16))) float f32x16;
typedef __attribute__((ext_vector_type(4))) unsigned short u16x4;
typedef __attribute__((ext_vector_type(8))) unsigned short u16x8;

// round-to-nearest-even f32 -> bf16
DEVI unsigned short f2bf(float f) {
    union { float f; unsigned u; } v; v.f = f;
    unsigned r = v.u + 0x7fffu + ((v.u >> 16) & 1u);
    return (unsigned short)(r >> 16);
}

// pack two f32 -> two bf16 in one dword (RNE), hw instruction
DEVI unsigned cvtpk(float lo, float hi) {
    unsigned r;
    asm("v_cvt_pk_bf16_f32 %0, %1, %2" : "=v"(r) : "v"(lo), "v"(hi));
    return r;
}

// async global->LDS, 16B per lane. LDS dest = wave-uniform base + lane*16.
DEVI void gload16(const void* g, void* lds) {
    __builtin_amdgcn_global_load_lds(
        (const __attribute__((address_space(1))) unsigned int*)(uintptr_t)g,
        (__attribute__((address_space(3))) unsigned int*)(unsigned int)(uintptr_t)lds,
        16, 0, 0);
}

// ---------------------------------------------------------------- convert
__global__ __launch_bounds__(256) void cvt_bf16(const float* __restrict__ in,
                                                unsigned short* __restrict__ out, int n4) {
    int i = blockIdx.x * 256 + threadIdx.x;
    if (i >= n4) return;
    float4 v = ((const float4*)in)[i];
    u16x4 pk;
    pk[0] = f2bf(v.x); pk[1] = f2bf(v.y); pk[2] = f2bf(v.z); pk[3] = f2bf(v.w);
    ((u16x4*)out)[i] = pk;
}

// ------------------------------------------------------- 4-phase GEMM core
// C[m][n] = sum_k A[m][k]*W[n][k], tile 128x256, BK=64, K=2048, 32 K-tiles.
// 8 waves (2x4), per-wave 64x64 = quadrants (qm,qn) of 32x32, 8 MFMA/phase.
// LDS: A 2x16KB + B 2x32KB = 96KB, rows 128B = 8x16B segs, seg ^= (row&7)
// (pre-swizzled global source, linear gload dest, swizzled ds_read).
// Stage stream = 64-row units [B0,B1,B2,B3,A0,A1], 1.5 tiles ahead;
// counted vmcnt(3) per tile (0 only at drain). Race-safety: B writes for
// tile kt+2 issue after ph1-end barrier (all B reads of kt complete);
// A writes always target the opposite buffer.
DEVI void gemm_pipe_core(const unsigned short* __restrict__ A,
                         const unsigned short* __restrict__ Wt,
                         int m0, int n0, char* lds,
                         f32x4 (&acc)[2][2][2][2]) {
    constexpr int K = 2048;
    const int t = threadIdx.x;
    const int w = t >> 6, l = t & 63, lr = l & 15, lk = l >> 4;
    const int wr = w >> 2, wc = w & 3;
    const int sx = lr & 7;  // read-side row-XOR (row ≡ lr mod 8 for all frags)
    const int srow = t >> 3, sseg = (t & 7) ^ (srow & 7);
    const unsigned short* aS = A + (size_t)(m0 + srow) * K + sseg * 8;
    const unsigned short* bS = Wt + (size_t)(n0 + srow) * K + sseg * 8;
    char* Bbase = lds + 32768;

#pragma unroll
    for (int qm = 0; qm < 2; qm++)
#pragma unroll
        for (int qn = 0; qn < 2; qn++)
#pragma unroll
            for (int fr = 0; fr < 2; fr++)
#pragma unroll
                for (int fc = 0; fc < 2; fc++)
                    acc[qm][qn][fr][fc] = (f32x4){0.f, 0.f, 0.f, 0.f};

    auto STAGE = [&](int tt, int u) {
        if (tt >= 32) return;
        const int k0 = tt * 64, bb = tt & 1;
        if (u < 4)
            gload16(bS + (size_t)u * 64 * K + k0, Bbase + bb * 32768 + u * 8192 + w * 1024);
        else
            gload16(aS + (size_t)(u - 4) * 64 * K + k0, lds + bb * 16384 + (u - 4) * 8192 + w * 1024);
    };

    // prologue: tile0 fully + B0,B1,B2 of tile1  (9 loads; keep 3 in flight)
    STAGE(0, 0); STAGE(0, 1); STAGE(0, 2); STAGE(0, 3); STAGE(0, 4); STAGE(0, 5);
    STAGE(1, 0); STAGE(1, 1); STAGE(1, 2);
    asm volatile("s_waitcnt vmcnt(3)" ::: "memory");
    __builtin_amdgcn_s_barrier();

    for (int kt = 0; kt < 32; ++kt) {
        const int bb = kt & 1;
        const char* Ab = lds + bb * 16384;
        const char* Bb = Bbase + bb * 32768;
        bf16x8 a0[2][2], a1[2][2], b0[2][2], b1[2][2];
        // ---- phase 0: read A(qm0)+B(qn0); stage (kt+1): B3, A0
#pragma unroll
        for (int fr = 0; fr < 2; fr++)
#pragma unroll
            for (int ks = 0; ks < 2; ks++)
                a0[fr][ks] = *(const bf16x8*)(Ab + (wr * 64 + fr * 16 + lr) * 128 +
                                              (((ks * 4 + lk) ^ sx) << 4));
#pragma unroll
        for (int fc = 0; fc < 2; fc++)
#pragma unroll
            for (int ks = 0; ks < 2; ks++)
                b0[fc][ks] = *(const bf16x8*)(Bb + (wc * 64 + fc * 16 + lr) * 128 +
                                              (((ks * 4 + lk) ^ sx) << 4));
        STAGE(kt + 1, 3); STAGE(kt + 1, 4);
        __builtin_amdgcn_s_barrier();
        __builtin_amdgcn_s_setprio(1);
#pragma unroll
        for (int ks = 0; ks < 2; ks++)
#pragma unroll
            for (int fr = 0; fr < 2; fr++)
#pragma unroll
                for (int fc = 0; fc < 2; fc++)
                    acc[0][0][fr][fc] = __builtin_amdgcn_mfma_f32_16x16x32_bf16(
                        a0[fr][ks], b0[fc][ks], acc[0][0][fr][fc], 0, 0, 0);
        __builtin_amdgcn_s_setprio(0);
        __builtin_amdgcn_s_barrier();
        // ---- phase 1: read B(qn1); stage (kt+1): A1
#pragma unroll
        for (int fc = 0; fc < 2; fc++)
#pragma unroll
            for (int ks = 0; ks < 2; ks++)
                b1[fc][ks] = *(const bf16x8*)(Bb + (wc * 64 + 32 + fc * 16 + lr) * 128 +
                                              (((ks * 4 + lk) ^ sx) << 4));
        STAGE(kt + 1, 5);
        __builtin_amdgcn_s_barrier();
        __builtin_amdgcn_s_setprio(1);
#pragma unroll
        for (int ks = 0; ks < 2; ks++)
#pragma unroll
            for (int fr = 0; fr < 2; fr++)
#pragma unroll
                for (int fc = 0; fc < 2; fc++)
                    acc[0][1][fr][fc] = __builtin_amdgcn_mfma_f32_16x16x32_bf16(
                        a0[fr][ks], b1[fc][ks], acc[0][1][fr][fc], 0, 0, 0);
        __builtin_amdgcn_s_setprio(0);
        __builtin_amdgcn_s_barrier();
        // ---- phase 2: read A(qm1); stage (kt+2): B0, B1  (B reads of kt done)
#pragma unroll
        for (int fr = 0; fr < 2; fr++)
#pragma unroll
            for (int ks = 0; ks < 2; ks++)
                a1[fr][ks] = *(const bf16x8*)(Ab + (wr * 64 + 32 + fr * 16 + lr) * 128 +
                                              (((ks * 4 + lk) ^ sx) << 4));
        STAGE(kt + 2, 0); STAGE(kt + 2, 1);
        __builtin_amdgcn_s_barrier();
        __builtin_amdgcn_s_setprio(1);
#pragma unroll
        for (int ks = 0; ks < 2; ks++)
#pragma unroll
            for (int fr = 0; fr < 2; fr++)
#pragma unroll
                for (int fc = 0; fc < 2; fc++)
                    acc[1][1][fr][fc] = __builtin_amdgcn_mfma_f32_16x16x32_bf16(
                        a1[fr][ks], b1[fc][ks], acc[1][1][fr][fc], 0, 0, 0);
        __builtin_amdgcn_s_setprio(0);
        __builtin_amdgcn_s_barrier();
        // ---- phase 3: no reads (b0 held); stage (kt+2): B2; counted vmcnt
        STAGE(kt + 2, 2);
        __builtin_amdgcn_s_setprio(1);
#pragma unroll
        for (int ks = 0; ks < 2; ks++)
#pragma unroll
            for (int fr = 0; fr < 2; fr++)
#pragma unroll
                for (int fc = 0; fc < 2; fc++)
                    acc[1][0][fr][fc] = __builtin_amdgcn_mfma_f32_16x16x32_bf16(
                        a1[fr][ks], b0[fc][ks], acc[1][0][fr][fc], 0, 0, 0);
        __builtin_amdgcn_s_setprio(0);
        if (kt < 30)       asm volatile("s_waitcnt vmcnt(3)" ::: "memory");
        else if (kt == 30) asm volatile("s_waitcnt vmcnt(0)" ::: "memory");
        __builtin_amdgcn_s_barrier();
    }
}

// qkv: z=0 -> q (fp32), z=1 -> k (fp32), z=2 -> v (bf16, transposed to (B,H,HD,S))
__global__ __launch_bounds__(512, 2) void gemm_qkv(
    const unsigned short* __restrict__ A,
    const unsigned short* __restrict__ Wq16, const unsigned short* __restrict__ Wk16,
    const unsigned short* __restrict__ Wv16,
    const float* __restrict__ bq, const float* __restrict__ bk, const float* __restrict__ bv,
    float* __restrict__ qf, float* __restrict__ kf, unsigned short* __restrict__ Vt) {
    __shared__ char Lds[98304];
    const int bid = blockIdx.x;
    // XCD partition by n-tile; consecutive z share the A panel in L2
    const int nt = bid & 7, rem = bid >> 3;
    const int mt = rem / 3, z = rem % 3;
    const int m0 = mt * 128, n0 = nt * 256;
    const unsigned short* W = (z == 0) ? Wq16 : (z == 1) ? Wk16 : Wv16;
    const float* bias = (z == 0) ? bq : (z == 1) ? bk : bv;

    f32x4 acc[2][2][2][2];
    gemm_pipe_core(A, W, m0, n0, Lds, acc);

    const int t = threadIdx.x, w = t >> 6, l = t & 63, lr = l & 15, lk = l >> 4;
    const int wr = w >> 2, wc = w & 3;
#pragma unroll
    for (int qm = 0; qm < 2; qm++)
#pragma unroll
        for (int qn = 0; qn < 2; qn++)
#pragma unroll
            for (int fr = 0; fr < 2; fr++)
#pragma unroll
                for (int fc = 0; fc < 2; fc++) {
                    const int col = n0 + wc * 64 + qn * 32 + fc * 16 + lr;
                    const int rb = m0 + wr * 64 + qm * 32 + fr * 16 + lk * 4;
                    const float bb = bias[col];
                    if (z == 2) {
                        const int hh = col >> 7, d = col & 127;
                        const int b = rb >> 11, s = rb & 2047;
                        u16x4 pk;
#pragma unroll
                        for (int j = 0; j < 4; j++) pk[j] = f2bf(acc[qm][qn][fr][fc][j] + bb);
                        *(u16x4*)(Vt + ((size_t)((b * 16 + hh) * 128 + d)) * 2048 + s) = pk;
                    } else {
                        float* out = (z == 0) ? qf : kf;
#pragma unroll
                        for (int j = 0; j < 4; j++)
                            out[(size_t)(rb + j) * 2048 + col] = acc[qm][qn][fr][fc][j] + bb;
                    }
                }
}

__global__ __launch_bounds__(512, 2) void gemm_o(
    const unsigned short* __restrict__ A, const unsigned short* __restrict__ W16,
    const float* __restrict__ bo, float* __restrict__ out) {
    __shared__ char Lds[98304];
    const int bid = blockIdx.x;
    const int nt = bid & 7, mt = bid >> 3;
    const int m0 = mt * 128, n0 = nt * 256;

    f32x4 acc[2][2][2][2];
    gemm_pipe_core(A, W16, m0, n0, Lds, acc);

    const int t = threadIdx.x, w = t >> 6, l = t & 63, lr = l & 15, lk = l >> 4;
    const int wr = w >> 2, wc = w & 3;
#pragma unroll
    for (int qm = 0; qm < 2; qm++)
#pragma unroll
        for (int qn = 0; qn < 2; qn++)
#pragma unroll
            for (int fr = 0; fr < 2; fr++)
#pragma unroll
                for (int fc = 0; fc < 2; fc++) {
                    const int col = n0 + wc * 64 + qn * 32 + fc * 16 + lr;
                    const int rb = m0 + wr * 64 + qm * 32 + fr * 16 + lk * 4;
                    const float bb = bo[col];
#pragma unroll
                    for (int j = 0; j < 4; j++)
                        out[(size_t)(rb + j) * 2048 + col] = acc[qm][qn][fr][fc][j] + bb;
                }
}

// ---------------------------------------------------- RMSNorm (full DIM) + RoPE
// Q pre-scaled by 1/sqrt(HD)*log2(e) so attn softmax runs in base-2.
__global__ __launch_bounds__(256) void norm_rope(
    const float* __restrict__ qf, const float* __restrict__ kf,
    const float* __restrict__ nqw, const float* __restrict__ nkw,
    const float* __restrict__ fc, const float* __restrict__ fs,
    unsigned short* __restrict__ Qr, unsigned short* __restrict__ Kr) {
    const int row = blockIdx.x;
    const int which = blockIdx.y;
    const float* in = which ? kf : qf;
    const float* wv = which ? nkw : nqw;
    unsigned short* out = which ? Kr : Qr;
    const float qs = which ? 1.0f : 0.12751744f;  // 1/sqrt(128) * log2(e)
    const int t = threadIdx.x;
    const float* x = in + (size_t)row * 2048 + t * 8;
    float4 v0 = ((const float4*)x)[0];
    float4 v1 = ((const float4*)x)[1];
    float xv[8] = {v0.x, v0.y, v0.z, v0.w, v1.x, v1.y, v1.z, v1.w};
    float ss = 0.f;
#pragma unroll
    for (int e = 0; e < 8; e++) ss += xv[e] * xv[e];
#pragma unroll
    for (int m = 1; m < 64; m <<= 1) ss += __shfl_xor(ss, m, 64);
    __shared__ float red[4];
    if ((t & 63) == 0) red[t >> 6] = ss;
    __syncthreads();
    const float tot = red[0] + red[1] + red[2] + red[3];
    const float r = rsqrtf(tot * (1.0f / 2048.0f) + 1e-6f);
    const int s = row & 2047, b = row >> 11;
    const int d0 = t * 8, hd0 = d0 & 127, h = d0 >> 7;
    float4 c0 = ((const float4*)(fc + s * 128 + hd0))[0];
    float4 c1 = ((const float4*)(fc + s * 128 + hd0))[1];
    float4 s0 = ((const float4*)(fs + s * 128 + hd0))[0];
    float4 s1 = ((const float4*)(fs + s * 128 + hd0))[1];
    float4 w0 = ((const float4*)(wv + d0))[0];
    float4 w1 = ((const float4*)(wv + d0))[1];
    float wn[8] = {w0.x, w0.y, w0.z, w0.w, w1.x, w1.y, w1.z, w1.w};
    float xn[8];
#pragma unroll
    for (int e = 0; e < 8; e++) xn[e] = xv[e] * wn[e] * r;
    float o[8];
    o[0] = xn[0] * c0.x - xn[1] * s0.y;  o[1] = xn[0] * s0.y + xn[1] * c0.x;
    o[2] = xn[2] * c0.z - xn[3] * s0.w;  o[3] = xn[2] * s0.w + xn[3] * c0.z;
    o[4] = xn[4] * c1.x - xn[5] * s1.y;  o[5] = xn[4] * s1.y + xn[5] * c1.x;
    o[6] = xn[6] * c1.z - xn[7] * s1.w;  o[7] = xn[6] * s1.w + xn[7] * c1.z;
    u16x8 pk;
#pragma unroll
    for (int e = 0; e < 8; e++) pk[e] = f2bf(o[e] * qs);
    *(u16x8*)(out + ((size_t)((b * 16 + h) * 2048 + s)) * 128 + hd0) = pk;
}

// -------------------------------------------------------------- flash attn
// 8 waves x 32 q-rows (block = 256 q rows), KVBLK=64, swapped-QK 32x32x16 MFMA.
__global__ __launch_bounds__(512, 2) void attn(
    const unsigned short* __restrict__ Qr, const unsigned short* __restrict__ Kr,
    const unsigned short* __restrict__ Vt, unsigned short* __restrict__ Ao) {
    __shared__ unsigned short Kl[2][64 * 128];
    __shared__ unsigned short Vl[2][128 * 64];
    const int t = threadIdx.x, w = t >> 6, l = t & 63;
    const int ql = l & 31, h = l >> 5;
    const int bid = blockIdx.x;
    const int xcd = bid & 7, idx = bid >> 3;
    const int bh = xcd * 4 + (idx >> 3);
    const int q0 = (idx & 7) * 256 + w * 32;
    const int b = bh >> 4, head = bh & 15;

    const unsigned short* Qp = Qr + ((size_t)bh * 2048 + q0) * 128;
    bf16x8 qf[8];
#pragma unroll
    for (int c8 = 0; c8 < 8; c8++)
        qf[c8] = *(const bf16x8*)(Qp + ql * 128 + c8 * 16 + h * 8);

    f32x16 accO[4];
#pragma unroll
    for (int dt = 0; dt < 4; dt++)
#pragma unroll
        for (int r = 0; r < 16; r++) accO[dt][r] = 0.f;
    float mj = -1e30f, ljp = 0.f;

    const unsigned short* Kb = Kr + (size_t)bh * 2048 * 128;
    const unsigned short* Vb = Vt + (size_t)bh * 128 * 2048;
    const int krow = t >> 4, kseg = (t & 15) ^ (krow & 7);
    const int vrow = t >> 3, vseg = (t & 7) ^ (vrow & 7);

    auto STAGE = [&](int buf, int kv0) {
        char* kd = (char*)&Kl[buf][0] + w * 1024;
        char* vd = (char*)&Vl[buf][0] + w * 1024;
        gload16(Kb + (size_t)(kv0 + krow) * 128 + kseg * 8, kd);
        gload16(Kb + (size_t)(kv0 + 32 + krow) * 128 + kseg * 8, kd + 8192);
        gload16(Vb + (size_t)vrow * 2048 + kv0 + vseg * 8, vd);
        gload16(Vb + (size_t)(64 + vrow) * 2048 + kv0 + vseg * 8, vd + 8192);
    };

    const int qx = ql & 7;
    STAGE(0, 0);
    __syncthreads();
    int cur = 0;
    for (int it = 0; it < 32; ++it) {
        if (it < 31) STAGE(cur ^ 1, (it + 1) * 64);
        f32x16 S0, S1;
#pragma unroll
        for (int r = 0; r < 16; r++) { S0[r] = 0.f; S1[r] = 0.f; }
        __builtin_amdgcn_s_setprio(1);
#pragma unroll
        for (int c8 = 0; c8 < 8; c8++) {
            const int sg = ((c8 * 2 + h) ^ qx) << 4;
            bf16x8 k0 = *(const bf16x8*)((const char*)&Kl[cur][0] + ql * 256 + sg);
            bf16x8 k1 = *(const bf16x8*)((const char*)&Kl[cur][0] + (32 + ql) * 256 + sg);
            S0 = __builtin_amdgcn_mfma_f32_32x32x16_bf16(k0, qf[c8], S0, 0, 0, 0);
            S1 = __builtin_amdgcn_mfma_f32_32x32x16_bf16(k1, qf[c8], S1, 0, 0, 0);
        }
        __builtin_amdgcn_s_setprio(0);
        float mloc = S0[0];
#pragma unroll
        for (int r = 1; r < 16; r++) mloc = fmaxf(mloc, S0[r]);
#pragma unroll
        for (int r = 0; r < 16; r++) mloc = fmaxf(mloc, S1[r]);
        const float mx = fmaxf(mloc, __shfl_xor(mloc, 32, 64));
        if (!__all(mx <= mj + 8.0f)) {
            const float mn = fmaxf(mj, mx);
            const float corr = exp2f(mj - mn);
            mj = mn;
            ljp *= corr;
#pragma unroll
            for (int dt = 0; dt < 4; dt++)
#pragma unroll
                for (int r = 0; r < 16; r++) accO[dt][r] *= corr;
        }
        unsigned W[16];
        float lsum = 0.f;
#pragma unroll
        for (int i = 0; i < 8; i++) {
            const float pa = exp2f(S0[2 * i] - mj);
            const float pb = exp2f(S0[2 * i + 1] - mj);
            W[i] = cvtpk(pa, pb);
            lsum += pa + pb;
        }
#pragma unroll
        for (int i = 0; i < 8; i++) {
            const float pa = exp2f(S1[2 * i] - mj);
            const float pb = exp2f(S1[2 * i + 1] - mj);
            W[8 + i] = cvtpk(pa, pb);
            lsum += pa + pb;
        }
        ljp += lsum;
#pragma unroll
        for (int c = 0; c < 2; c++) {
            unsigned X[8];
#pragma unroll
            for (int i = 0; i < 8; i++)
                X[i] = (unsigned)__shfl_xor((int)W[c * 8 + i], 32, 64);
            union U { unsigned u[4]; bf16x8 v; };
            U F, G;
            F.u[0] = h ? X[2] : W[c * 8 + 0];
            F.u[1] = h ? X[3] : W[c * 8 + 1];
            F.u[2] = h ? W[c * 8 + 2] : X[0];
            F.u[3] = h ? W[c * 8 + 3] : X[1];
            G.u[0] = h ? X[6] : W[c * 8 + 4];
            G.u[1] = h ? X[7] : W[c * 8 + 5];
            G.u[2] = h ? W[c * 8 + 6] : X[4];
            G.u[3] = h ? W[c * 8 + 7] : X[5];
            __builtin_amdgcn_s_setprio(1);
#pragma unroll
            for (int dt = 0; dt < 4; dt++) {
                const int sg = (((2 * c) * 2 + h) ^ qx) << 4;
                bf16x8 vf = *(const bf16x8*)((const char*)&Vl[cur][0] + (dt * 32 + ql) * 128 + sg);
                accO[dt] = __builtin_amdgcn_mfma_f32_32x32x16_bf16(vf, F.v, accO[dt], 0, 0, 0);
            }
#pragma unroll
            for (int dt = 0; dt < 4; dt++) {
                const int sg = (((2 * c + 1) * 2 + h) ^ qx) << 4;
                bf16x8 vf = *(const bf16x8*)((const char*)&Vl[cur][0] + (dt * 32 + ql) * 128 + sg);
                accO[dt] = __builtin_amdgcn_mfma_f32_32x32x16_bf16(vf, G.v, accO[dt], 0, 0, 0);
            }
            __builtin_amdgcn_s_setprio(0);
        }
        __syncthreads();
        cur ^= 1;
    }
    const float lj = ljp + __shfl_xor(ljp, 32, 64);
    const float inv = 1.0f / lj;
    unsigned short* ob = Ao + ((size_t)(b * 2048 + q0 + ql)) * 2048 + head * 128;
#pragma unroll
    for (int dt = 0; dt < 4; dt++)
#pragma unroll
        for (int i = 0; i < 8; i++) {
            const float a = accO[dt][2 * i] * inv;
            const float c = accO[dt][2 * i + 1] * inv;
            const int d = dt * 32 + ((2 * i) & 3) + 8 * (i >> 1) + 4 * h;
            *(unsigned*)(ob + d) = cvtpk(a, c);
        }
}

// ------------------------------------------------------------------ launch
extern "C" void kernel_launch(void* const* d_in, const int* in_sizes, int n_in,
                              void* d_out, int out_size, void* d_ws, size_t ws_size,
                              hipStream_t stream) {
    const float* hs  = (const float*)d_in[0];
    const float* fc  = (const float*)d_in[1];
    const float* fs  = (const float*)d_in[2];
    const float* Wq  = (const float*)d_in[3];
    const float* bq  = (const float*)d_in[4];
    const float* Wk  = (const float*)d_in[5];
    const float* bk  = (const float*)d_in[6];
    const float* Wv  = (const float*)d_in[7];
    const float* bv  = (const float*)d_in[8];
    const float* nqw = (const float*)d_in[9];
    const float* nkw = (const float*)d_in[10];
    const float* Wo  = (const float*)d_in[11];
    const float* bo  = (const float*)d_in[12];
    float* out = (float*)d_out;

    char* p = (char*)d_ws;
    unsigned short* hs16 = (unsigned short*)p; p += (size_t)8388608 * 2;
    unsigned short* Wq16 = (unsigned short*)p; p += (size_t)4194304 * 2;
    unsigned short* Wk16 = (unsigned short*)p; p += (size_t)4194304 * 2;
    unsigned short* Wv16 = (unsigned short*)p; p += (size_t)4194304 * 2;
    unsigned short* Wo16 = (unsigned short*)p; p += (size_t)4194304 * 2;
    float* qf = (float*)p;                     p += (size_t)8388608 * 4;
    float* kf = (float*)p;                     p += (size_t)8388608 * 4;
    unsigned short* Qr = (unsigned short*)p;   p += (size_t)8388608 * 2;
    unsigned short* Kr = (unsigned short*)p;   p += (size_t)8388608 * 2;
    unsigned short* Vt = (unsigned short*)p;   p += (size_t)8388608 * 2;
    unsigned short* Ao = (unsigned short*)p;   p += (size_t)8388608 * 2;
    (void)ws_size; (void)in_sizes; (void)n_in; (void)out_size;

    cvt_bf16<<<8192, 256, 0, stream>>>(hs, hs16, 2097152);
    cvt_bf16<<<4096, 256, 0, stream>>>(Wq, Wq16, 1048576);
    cvt_bf16<<<4096, 256, 0, stream>>>(Wk, Wk16, 1048576);
    cvt_bf16<<<4096, 256, 0, stream>>>(Wv, Wv16, 1048576);
    cvt_bf16<<<4096, 256, 0, stream>>>(Wo, Wo16, 1048576);

    gemm_qkv<<<768, 512, 0, stream>>>(hs16, Wq16, Wk16, Wv16,
                                      bq, bk, bv, qf, kf, Vt);
    norm_rope<<<dim3(4096, 2), 256, 0, stream>>>(qf, kf, nqw, nkw, fc, fs, Qr, Kr);
    attn<<<256, 512, 0, stream>>>(Qr, Kr, Vt, Ao);
    gemm_o<<<256, 512, 0, stream>>>(Ao, Wo16, bo, out);
}

// Round 6
// 303.303 us; speedup vs baseline: 1.6833x; 1.0391x over previous
//
#include <hip/hip_runtime.h>
#include <stdint.h>

#define DEVI __device__ __forceinline__

typedef __attribute__((ext_vector_type(8))) short bf16x8;
typedef __attribute__((ext_vector_type(4))) float f32x4;
typedef __attribute__((ext_vector_type(16))) float f32x16;
typedef __attribute__((ext_vector_type(4))) unsigned short u16x4;
typedef __attribute__((ext_vector_type(8))) unsigned short u16x8;

// round-to-nearest-even f32 -> bf16
DEVI unsigned short f2bf(float f) {
    union { float f; unsigned u; } v; v.f = f;
    unsigned r = v.u + 0x7fffu + ((v.u >> 16) & 1u);
    return (unsigned short)(r >> 16);
}

// pack two f32 -> two bf16 in one dword (RNE), hw instruction
DEVI unsigned cvtpk(float lo, float hi) {
    unsigned r;
    asm("v_cvt_pk_bf16_f32 %0, %1, %2" : "=v"(r) : "v"(lo), "v"(hi));
    return r;
}

// async global->LDS, 16B per lane. LDS dest = wave-uniform base + lane*16.
DEVI void gload16(const void* g, void* lds) {
    __builtin_amdgcn_global_load_lds(
        (const __attribute__((address_space(1))) unsigned int*)(uintptr_t)g,
        (__attribute__((address_space(3))) unsigned int*)(unsigned int)(uintptr_t)lds,
        16, 0, 0);
}

// ------------------------------------------------ fused convert (one launch)
// blocks [0,2048): hs, [2048,3072): Wq, [3072,4096): Wk, [4096,5120): Wv,
// [5120,6144): Wo. Each block converts 1024 float4 (16KB fp32 -> 8KB bf16).
__global__ __launch_bounds__(256) void cvt_all(
    const float* __restrict__ hs, const float* __restrict__ wq,
    const float* __restrict__ wk, const float* __restrict__ wv,
    const float* __restrict__ wo,
    unsigned short* __restrict__ o_hs, unsigned short* __restrict__ o_wq,
    unsigned short* __restrict__ o_wk, unsigned short* __restrict__ o_wv,
    unsigned short* __restrict__ o_wo) {
    const int bid = blockIdx.x;
    const float* src; unsigned short* dst; int base;
    if (bid < 2048)      { src = hs; dst = o_hs; base = bid; }
    else if (bid < 3072) { src = wq; dst = o_wq; base = bid - 2048; }
    else if (bid < 4096) { src = wk; dst = o_wk; base = bid - 3072; }
    else if (bid < 5120) { src = wv; dst = o_wv; base = bid - 4096; }
    else                 { src = wo; dst = o_wo; base = bid - 5120; }
    const int i0 = base * 1024 + threadIdx.x;
#pragma unroll
    for (int k = 0; k < 4; k++) {
        const int i = i0 + k * 256;
        float4 v = ((const float4*)src)[i];
        u16x4 pk;
        pk[0] = f2bf(v.x); pk[1] = f2bf(v.y); pk[2] = f2bf(v.z); pk[3] = f2bf(v.w);
        ((u16x4*)dst)[i] = pk;
    }
}

// ------------------------------------------------------- 2-phase GEMM core
// C[m][n] = sum_k A[m][k]*W[n][k], tile 128x256, BK=64, K=2048, 32 K-tiles.
// 8 waves (2x4), per-wave 64x64 = quadrants (qm,qn), 16 MFMA 16x16x32/phase.
// LDS: A 2x16KB + B 2x32KB = 96KB, rows 128B = 8x16B segs, seg ^= (row&7)
// (pre-swizzled global source, linear gload dest, swizzled ds_read).
// Per tile: all 16 ds_reads up front; phase A = stage(kt+1:B3,A0,A1) +
// 16 MFMA(qn0) + lgkmcnt(0) + bar; phase B = stage(kt+2:B0,B1,B2) +
// 16 MFMA(qn1) + vmcnt(3) + bar. Only 2 barriers/tile; no pre-MFMA barrier
// (waves de-lockstep by <=1 phase -> partner-wave ds_read/MFMA overlap).
// Race proof: kt+2 same-parity B writes issue after post-A bar; every wave
// executed lgkmcnt(0) (all B reads of kt done) before that bar. A writes
// always target opposite parity. Counted vmcnt: in-flight at tile end =
// 3 (kt+1 units) + 3 (kt+2 units) -> vmcnt(3) completes tile kt+1 exactly.
DEVI void gemm_pipe_core(const unsigned short* __restrict__ A,
                         const unsigned short* __restrict__ Wt,
                         int m0, int n0, char* lds,
                         f32x4 (&acc)[2][2][2][2]) {
    constexpr int K = 2048;
    const int t = threadIdx.x;
    const int w = t >> 6, l = t & 63, lr = l & 15, lk = l >> 4;
    const int wr = w >> 2, wc = w & 3;
    const int sx = lr & 7;  // read-side row-XOR (row ≡ lr mod 8 for all frags)
    const int srow = t >> 3, sseg = (t & 7) ^ (srow & 7);
    const unsigned short* aS = A + (size_t)(m0 + srow) * K + sseg * 8;
    const unsigned short* bS = Wt + (size_t)(n0 + srow) * K + sseg * 8;
    char* Bbase = lds + 32768;

#pragma unroll
    for (int qm = 0; qm < 2; qm++)
#pragma unroll
        for (int qn = 0; qn < 2; qn++)
#pragma unroll
            for (int fr = 0; fr < 2; fr++)
#pragma unroll
                for (int fc = 0; fc < 2; fc++)
                    acc[qm][qn][fr][fc] = (f32x4){0.f, 0.f, 0.f, 0.f};

    auto STAGE = [&](int tt, int u) {
        if (tt >= 32) return;
        const int k0 = tt * 64, bb = tt & 1;
        if (u < 4)
            gload16(bS + (size_t)u * 64 * K + k0, Bbase + bb * 32768 + u * 8192 + w * 1024);
        else
            gload16(aS + (size_t)(u - 4) * 64 * K + k0, lds + bb * 16384 + (u - 4) * 8192 + w * 1024);
    };

    // prologue: tile0 fully + B0,B1,B2 of tile1 (9 loads; leave 3 in flight)
    STAGE(0, 0); STAGE(0, 1); STAGE(0, 2); STAGE(0, 3); STAGE(0, 4); STAGE(0, 5);
    STAGE(1, 0); STAGE(1, 1); STAGE(1, 2);
    asm volatile("s_waitcnt vmcnt(3)" ::: "memory");
    __builtin_amdgcn_s_barrier();

    for (int kt = 0; kt < 32; ++kt) {
        const int bb = kt & 1;
        const char* Ab = lds + bb * 16384;
        const char* Bb = Bbase + bb * 32768;
        bf16x8 a0[2][2], a1[2][2], b0[2][2], b1[2][2];
        // ---- all reads for this tile
#pragma unroll
        for (int fr = 0; fr < 2; fr++)
#pragma unroll
            for (int ks = 0; ks < 2; ks++) {
                a0[fr][ks] = *(const bf16x8*)(Ab + (wr * 64 + fr * 16 + lr) * 128 +
                                              (((ks * 4 + lk) ^ sx) << 4));
                a1[fr][ks] = *(const bf16x8*)(Ab + (wr * 64 + 32 + fr * 16 + lr) * 128 +
                                              (((ks * 4 + lk) ^ sx) << 4));
            }
#pragma unroll
        for (int fc = 0; fc < 2; fc++)
#pragma unroll
            for (int ks = 0; ks < 2; ks++) {
                b0[fc][ks] = *(const bf16x8*)(Bb + (wc * 64 + fc * 16 + lr) * 128 +
                                              (((ks * 4 + lk) ^ sx) << 4));
                b1[fc][ks] = *(const bf16x8*)(Bb + (wc * 64 + 32 + fc * 16 + lr) * 128 +
                                              (((ks * 4 + lk) ^ sx) << 4));
            }
        // ---- phase A: stage kt+1 remainder, MFMA qn0
        STAGE(kt + 1, 3); STAGE(kt + 1, 4); STAGE(kt + 1, 5);
        __builtin_amdgcn_s_setprio(1);
#pragma unroll
        for (int ks = 0; ks < 2; ks++)
#pragma unroll
            for (int fr = 0; fr < 2; fr++)
#pragma unroll
                for (int fc = 0; fc < 2; fc++) {
                    acc[0][0][fr][fc] = __builtin_amdgcn_mfma_f32_16x16x32_bf16(
                        a0[fr][ks], b0[fc][ks], acc[0][0][fr][fc], 0, 0, 0);
                    acc[1][0][fr][fc] = __builtin_amdgcn_mfma_f32_16x16x32_bf16(
                        a1[fr][ks], b0[fc][ks], acc[1][0][fr][fc], 0, 0, 0);
                }
        __builtin_amdgcn_s_setprio(0);
        asm volatile("s_waitcnt lgkmcnt(0)" ::: "memory");  // all reads of kt done
        __builtin_amdgcn_s_barrier();
        // ---- phase B: stage kt+2 B0-B2 (same parity as kt: safe now), MFMA qn1
        STAGE(kt + 2, 0); STAGE(kt + 2, 1); STAGE(kt + 2, 2);
        __builtin_amdgcn_s_setprio(1);
#pragma unroll
        for (int ks = 0; ks < 2; ks++)
#pragma unroll
            for (int fr = 0; fr < 2; fr++)
#pragma unroll
                for (int fc = 0; fc < 2; fc++) {
                    acc[0][1][fr][fc] = __builtin_amdgcn_mfma_f32_16x16x32_bf16(
                        a0[fr][ks], b1[fc][ks], acc[0][1][fr][fc], 0, 0, 0);
                    acc[1][1][fr][fc] = __builtin_amdgcn_mfma_f32_16x16x32_bf16(
                        a1[fr][ks], b1[fc][ks], acc[1][1][fr][fc], 0, 0, 0);
                }
        __builtin_amdgcn_s_setprio(0);
        if (kt < 30)       asm volatile("s_waitcnt vmcnt(3)" ::: "memory");
        else if (kt == 30) asm volatile("s_waitcnt vmcnt(0)" ::: "memory");
        __builtin_amdgcn_s_barrier();
    }
}

// qkv: z=0 -> q (fp32), z=1 -> k (fp32), z=2 -> v (bf16, transposed to (B,H,HD,S))
__global__ __launch_bounds__(512, 2) void gemm_qkv(
    const unsigned short* __restrict__ A,
    const unsigned short* __restrict__ Wq16, const unsigned short* __restrict__ Wk16,
    const unsigned short* __restrict__ Wv16,
    const float* __restrict__ bq, const float* __restrict__ bk, const float* __restrict__ bv,
    float* __restrict__ qf, float* __restrict__ kf, unsigned short* __restrict__ Vt) {
    __shared__ char Lds[98304];
    const int bid = blockIdx.x;
    // XCD partition by n-tile; consecutive z share the A panel in L2
    const int nt = bid & 7, rem = bid >> 3;
    const int mt = rem / 3, z = rem % 3;
    const int m0 = mt * 128, n0 = nt * 256;
    const unsigned short* W = (z == 0) ? Wq16 : (z == 1) ? Wk16 : Wv16;
    const float* bias = (z == 0) ? bq : (z == 1) ? bk : bv;

    f32x4 acc[2][2][2][2];
    gemm_pipe_core(A, W, m0, n0, Lds, acc);

    const int t = threadIdx.x, w = t >> 6, l = t & 63, lr = l & 15, lk = l >> 4;
    const int wr = w >> 2, wc = w & 3;
#pragma unroll
    for (int qm = 0; qm < 2; qm++)
#pragma unroll
        for (int qn = 0; qn < 2; qn++)
#pragma unroll
            for (int fr = 0; fr < 2; fr++)
#pragma unroll
                for (int fc = 0; fc < 2; fc++) {
                    const int col = n0 + wc * 64 + qn * 32 + fc * 16 + lr;
                    const int rb = m0 + wr * 64 + qm * 32 + fr * 16 + lk * 4;
                    const float bb = bias[col];
                    if (z == 2) {
                        const int hh = col >> 7, d = col & 127;
                        const int b = rb >> 11, s = rb & 2047;
                        u16x4 pk;
#pragma unroll
                        for (int j = 0; j < 4; j++) pk[j] = f2bf(acc[qm][qn][fr][fc][j] + bb);
                        *(u16x4*)(Vt + ((size_t)((b * 16 + hh) * 128 + d)) * 2048 + s) = pk;
                    } else {
                        float* out = (z == 0) ? qf : kf;
#pragma unroll
                        for (int j = 0; j < 4; j++)
                            out[(size_t)(rb + j) * 2048 + col] = acc[qm][qn][fr][fc][j] + bb;
                    }
                }
}

__global__ __launch_bounds__(512, 2) void gemm_o(
    const unsigned short* __restrict__ A, const unsigned short* __restrict__ W16,
    const float* __restrict__ bo, float* __restrict__ out) {
    __shared__ char Lds[98304];
    const int bid = blockIdx.x;
    const int nt = bid & 7, mt = bid >> 3;
    const int m0 = mt * 128, n0 = nt * 256;

    f32x4 acc[2][2][2][2];
    gemm_pipe_core(A, W16, m0, n0, Lds, acc);

    const int t = threadIdx.x, w = t >> 6, l = t & 63, lr = l & 15, lk = l >> 4;
    const int wr = w >> 2, wc = w & 3;
#pragma unroll
    for (int qm = 0; qm < 2; qm++)
#pragma unroll
        for (int qn = 0; qn < 2; qn++)
#pragma unroll
            for (int fr = 0; fr < 2; fr++)
#pragma unroll
                for (int fc = 0; fc < 2; fc++) {
                    const int col = n0 + wc * 64 + qn * 32 + fc * 16 + lr;
                    const int rb = m0 + wr * 64 + qm * 32 + fr * 16 + lk * 4;
                    const float bb = bo[col];
#pragma unroll
                    for (int j = 0; j < 4; j++)
                        out[(size_t)(rb + j) * 2048 + col] = acc[qm][qn][fr][fc][j] + bb;
                }
}

// ---------------------------------------------------- RMSNorm (full DIM) + RoPE
// Q pre-scaled by 1/sqrt(HD)*log2(e) so attn softmax runs in base-2.
__global__ __launch_bounds__(256) void norm_rope(
    const float* __restrict__ qf, const float* __restrict__ kf,
    const float* __restrict__ nqw, const float* __restrict__ nkw,
    const float* __restrict__ fc, const float* __restrict__ fs,
    unsigned short* __restrict__ Qr, unsigned short* __restrict__ Kr) {
    const int row = blockIdx.x;
    const int which = blockIdx.y;
    const float* in = which ? kf : qf;
    const float* wv = which ? nkw : nqw;
    unsigned short* out = which ? Kr : Qr;
    const float qs = which ? 1.0f : 0.12751744f;  // 1/sqrt(128) * log2(e)
    const int t = threadIdx.x;
    const float* x = in + (size_t)row * 2048 + t * 8;
    float4 v0 = ((const float4*)x)[0];
    float4 v1 = ((const float4*)x)[1];
    float xv[8] = {v0.x, v0.y, v0.z, v0.w, v1.x, v1.y, v1.z, v1.w};
    float ss = 0.f;
#pragma unroll
    for (int e = 0; e < 8; e++) ss += xv[e] * xv[e];
#pragma unroll
    for (int m = 1; m < 64; m <<= 1) ss += __shfl_xor(ss, m, 64);
    __shared__ float red[4];
    if ((t & 63) == 0) red[t >> 6] = ss;
    __syncthreads();
    const float tot = red[0] + red[1] + red[2] + red[3];
    const float r = rsqrtf(tot * (1.0f / 2048.0f) + 1e-6f);
    const int s = row & 2047, b = row >> 11;
    const int d0 = t * 8, hd0 = d0 & 127, h = d0 >> 7;
    float4 c0 = ((const float4*)(fc + s * 128 + hd0))[0];
    float4 c1 = ((const float4*)(fc + s * 128 + hd0))[1];
    float4 s0 = ((const float4*)(fs + s * 128 + hd0))[0];
    float4 s1 = ((const float4*)(fs + s * 128 + hd0))[1];
    float4 w0 = ((const float4*)(wv + d0))[0];
    float4 w1 = ((const float4*)(wv + d0))[1];
    float wn[8] = {w0.x, w0.y, w0.z, w0.w, w1.x, w1.y, w1.z, w1.w};
    float xn[8];
#pragma unroll
    for (int e = 0; e < 8; e++) xn[e] = xv[e] * wn[e] * r;
    float o[8];
    o[0] = xn[0] * c0.x - xn[1] * s0.y;  o[1] = xn[0] * s0.y + xn[1] * c0.x;
    o[2] = xn[2] * c0.z - xn[3] * s0.w;  o[3] = xn[2] * s0.w + xn[3] * c0.z;
    o[4] = xn[4] * c1.x - xn[5] * s1.y;  o[5] = xn[4] * s1.y + xn[5] * c1.x;
    o[6] = xn[6] * c1.z - xn[7] * s1.w;  o[7] = xn[6] * s1.w + xn[7] * c1.z;
    u16x8 pk;
#pragma unroll
    for (int e = 0; e < 8; e++) pk[e] = f2bf(o[e] * qs);
    *(u16x8*)(out + ((size_t)((b * 16 + h) * 2048 + s)) * 128 + hd0) = pk;
}

// -------------------------------------------------------------- flash attn
// 8 waves x 32 q-rows (block = 256 q rows), KVBLK=64, swapped-QK 32x32x16 MFMA.
__global__ __launch_bounds__(512, 2) void attn(
    const unsigned short* __restrict__ Qr, const unsigned short* __restrict__ Kr,
    const unsigned short* __restrict__ Vt, unsigned short* __restrict__ Ao) {
    __shared__ unsigned short Kl[2][64 * 128];
    __shared__ unsigned short Vl[2][128 * 64];
    const int t = threadIdx.x, w = t >> 6, l = t & 63;
    const int ql = l & 31, h = l >> 5;
    const int bid = blockIdx.x;
    const int xcd = bid & 7, idx = bid >> 3;
    const int bh = xcd * 4 + (idx >> 3);
    const int q0 = (idx & 7) * 256 + w * 32;
    const int b = bh >> 4, head = bh & 15;

    const unsigned short* Qp = Qr + ((size_t)bh * 2048 + q0) * 128;
    bf16x8 qf[8];
#pragma unroll
    for (int c8 = 0; c8 < 8; c8++)
        qf[c8] = *(const bf16x8*)(Qp + ql * 128 + c8 * 16 + h * 8);

    f32x16 accO[4];
#pragma unroll
    for (int dt = 0; dt < 4; dt++)
#pragma unroll
        for (int r = 0; r < 16; r++) accO[dt][r] = 0.f;
    float mj = -1e30f, ljp = 0.f;

    const unsigned short* Kb = Kr + (size_t)bh * 2048 * 128;
    const unsigned short* Vb = Vt + (size_t)bh * 128 * 2048;
    const int krow = t >> 4, kseg = (t & 15) ^ (krow & 7);
    const int vrow = t >> 3, vseg = (t & 7) ^ (vrow & 7);

    auto STAGE = [&](int buf, int kv0) {
        char* kd = (char*)&Kl[buf][0] + w * 1024;
        char* vd = (char*)&Vl[buf][0] + w * 1024;
        gload16(Kb + (size_t)(kv0 + krow) * 128 + kseg * 8, kd);
        gload16(Kb + (size_t)(kv0 + 32 + krow) * 128 + kseg * 8, kd + 8192);
        gload16(Vb + (size_t)vrow * 2048 + kv0 + vseg * 8, vd);
        gload16(Vb + (size_t)(64 + vrow) * 2048 + kv0 + vseg * 8, vd + 8192);
    };

    const int qx = ql & 7;
    STAGE(0, 0);
    __syncthreads();
    int cur = 0;
    for (int it = 0; it < 32; ++it) {
        if (it < 31) STAGE(cur ^ 1, (it + 1) * 64);
        f32x16 S0, S1;
#pragma unroll
        for (int r = 0; r < 16; r++) { S0[r] = 0.f; S1[r] = 0.f; }
        __builtin_amdgcn_s_setprio(1);
#pragma unroll
        for (int c8 = 0; c8 < 8; c8++) {
            const int sg = ((c8 * 2 + h) ^ qx) << 4;
            bf16x8 k0 = *(const bf16x8*)((const char*)&Kl[cur][0] + ql * 256 + sg);
            bf16x8 k1 = *(const bf16x8*)((const char*)&Kl[cur][0] + (32 + ql) * 256 + sg);
            S0 = __builtin_amdgcn_mfma_f32_32x32x16_bf16(k0, qf[c8], S0, 0, 0, 0);
            S1 = __builtin_amdgcn_mfma_f32_32x32x16_bf16(k1, qf[c8], S1, 0, 0, 0);
        }
        __builtin_amdgcn_s_setprio(0);
        float mloc = S0[0];
#pragma unroll
        for (int r = 1; r < 16; r++) mloc = fmaxf(mloc, S0[r]);
#pragma unroll
        for (int r = 0; r < 16; r++) mloc = fmaxf(mloc, S1[r]);
        const float mx = fmaxf(mloc, __shfl_xor(mloc, 32, 64));
        if (!__all(mx <= mj + 8.0f)) {
            const float mn = fmaxf(mj, mx);
            const float corr = exp2f(mj - mn);
            mj = mn;
            ljp *= corr;
#pragma unroll
            for (int dt = 0; dt < 4; dt++)
#pragma unroll
                for (int r = 0; r < 16; r++) accO[dt][r] *= corr;
        }
        unsigned W[16];
        float lsum = 0.f;
#pragma unroll
        for (int i = 0; i < 8; i++) {
            const float pa = exp2f(S0[2 * i] - mj);
            const float pb = exp2f(S0[2 * i + 1] - mj);
            W[i] = cvtpk(pa, pb);
            lsum += pa + pb;
        }
#pragma unroll
        for (int i = 0; i < 8; i++) {
            const float pa = exp2f(S1[2 * i] - mj);
            const float pb = exp2f(S1[2 * i + 1] - mj);
            W[8 + i] = cvtpk(pa, pb);
            lsum += pa + pb;
        }
        ljp += lsum;
#pragma unroll
        for (int c = 0; c < 2; c++) {
            unsigned X[8];
#pragma unroll
            for (int i = 0; i < 8; i++)
                X[i] = (unsigned)__shfl_xor((int)W[c * 8 + i], 32, 64);
            union U { unsigned u[4]; bf16x8 v; };
            U F, G;
            F.u[0] = h ? X[2] : W[c * 8 + 0];
            F.u[1] = h ? X[3] : W[c * 8 + 1];
            F.u[2] = h ? W[c * 8 + 2] : X[0];
            F.u[3] = h ? W[c * 8 + 3] : X[1];
            G.u[0] = h ? X[6] : W[c * 8 + 4];
            G.u[1] = h ? X[7] : W[c * 8 + 5];
            G.u[2] = h ? W[c * 8 + 6] : X[4];
            G.u[3] = h ? W[c * 8 + 7] : X[5];
            __builtin_amdgcn_s_setprio(1);
#pragma unroll
            for (int dt = 0; dt < 4; dt++) {
                const int sg = (((2 * c) * 2 + h) ^ qx) << 4;
                bf16x8 vf = *(const bf16x8*)((const char*)&Vl[cur][0] + (dt * 32 + ql) * 128 + sg);
                accO[dt] = __builtin_amdgcn_mfma_f32_32x32x16_bf16(vf, F.v, accO[dt], 0, 0, 0);
            }
#pragma unroll
            for (int dt = 0; dt < 4; dt++) {
                const int sg = (((2 * c + 1) * 2 + h) ^ qx) << 4;
                bf16x8 vf = *(const bf16x8*)((const char*)&Vl[cur][0] + (dt * 32 + ql) * 128 + sg);
                accO[dt] = __builtin_amdgcn_mfma_f32_32x32x16_bf16(vf, G.v, accO[dt], 0, 0, 0);
            }
            __builtin_amdgcn_s_setprio(0);
        }
        __syncthreads();
        cur ^= 1;
    }
    const float lj = ljp + __shfl_xor(ljp, 32, 64);
    const float inv = 1.0f / lj;
    unsigned short* ob = Ao + ((size_t)(b * 2048 + q0 + ql)) * 2048 + head * 128;
#pragma unroll
    for (int dt = 0; dt < 4; dt++)
#pragma unroll
        for (int i = 0; i < 8; i++) {
            const float a = accO[dt][2 * i] * inv;
            const float c = accO[dt][2 * i + 1] * inv;
            const int d = dt * 32 + ((2 * i) & 3) + 8 * (i >> 1) + 4 * h;
            *(unsigned*)(ob + d) = cvtpk(a, c);
        }
}

// ------------------------------------------------------------------ launch
extern "C" void kernel_launch(void* const* d_in, const int* in_sizes, int n_in,
                              void* d_out, int out_size, void* d_ws, size_t ws_size,
                              hipStream_t stream) {
    const float* hs  = (const float*)d_in[0];
    const float* fc  = (const float*)d_in[1];
    const float* fs  = (const float*)d_in[2];
    const float* Wq  = (const float*)d_in[3];
    const float* bq  = (const float*)d_in[4];
    const float* Wk  = (const float*)d_in[5];
    const float* bk  = (const float*)d_in[6];
    const float* Wv  = (const float*)d_in[7];
    const float* bv  = (const float*)d_in[8];
    const float* nqw = (const float*)d_in[9];
    const float* nkw = (const float*)d_in[10];
    const float* Wo  = (const float*)d_in[11];
    const float* bo  = (const float*)d_in[12];
    float* out = (float*)d_out;

    char* p = (char*)d_ws;
    unsigned short* hs16 = (unsigned short*)p; p += (size_t)8388608 * 2;
    unsigned short* Wq16 = (unsigned short*)p; p += (size_t)4194304 * 2;
    unsigned short* Wk16 = (unsigned short*)p; p += (size_t)4194304 * 2;
    unsigned short* Wv16 = (unsigned short*)p; p += (size_t)4194304 * 2;
    unsigned short* Wo16 = (unsigned short*)p; p += (size_t)4194304 * 2;
    float* qf = (float*)p;                     p += (size_t)8388608 * 4;
    float* kf = (float*)p;                     p += (size_t)8388608 * 4;
    unsigned short* Qr = (unsigned short*)p;   p += (size_t)8388608 * 2;
    unsigned short* Kr = (unsigned short*)p;   p += (size_t)8388608 * 2;
    unsigned short* Vt = (unsigned short*)p;   p += (size_t)8388608 * 2;
    unsigned short* Ao = (unsigned short*)p;   p += (size_t)8388608 * 2;
    (void)ws_size; (void)in_sizes; (void)n_in; (void)out_size;

    cvt_all<<<6144, 256, 0, stream>>>(hs, Wq, Wk, Wv, Wo,
                                      hs16, Wq16, Wk16, Wv16, Wo16);
    gemm_qkv<<<768, 512, 0, stream>>>(hs16, Wq16, Wk16, Wv16,
                                      bq, bk, bv, qf, kf, Vt);
    norm_rope<<<dim3(4096, 2), 256, 0, stream>>>(qf, kf, nqw, nkw, fc, fs, Qr, Kr);
    attn<<<256, 512, 0, stream>>>(Qr, Kr, Vt, Ao);
    gemm_o<<<256, 512, 0, stream>>>(Ao, Wo16, bo, out);
}

// Round 9
// 301.030 us; speedup vs baseline: 1.6960x; 1.0076x over previous
//
#include <hip/hip_runtime.h>
#include <stdint.h>

#define DEVI __device__ __forceinline__

typedef __attribute__((ext_vector_type(8))) short bf16x8;
typedef __attribute__((ext_vector_type(4))) float f32x4;
typedef __attribute__((ext_vector_type(16))) float f32x16;
typedef __attribute__((ext_vector_type(4))) unsigned short u16x4;
typedef __attribute__((ext_vector_type(8))) unsigned short u16x8;

// round-to-nearest-even f32 -> bf16
DEVI unsigned short f2bf(float f) {
    union { float f; unsigned u; } v; v.f = f;
    unsigned r = v.u + 0x7fffu + ((v.u >> 16) & 1u);
    return (unsigned short)(r >> 16);
}

// pack two f32 -> two bf16 in one dword (RNE), hw instruction
DEVI unsigned cvtpk(float lo, float hi) {
    unsigned r;
    asm("v_cvt_pk_bf16_f32 %0, %1, %2" : "=v"(r) : "v"(lo), "v"(hi));
    return r;
}

// async global->LDS, 16B per lane. LDS dest = wave-uniform base + lane*16.
DEVI void gload16(const void* g, void* lds) {
    __builtin_amdgcn_global_load_lds(
        (const __attribute__((address_space(1))) unsigned int*)(uintptr_t)g,
        (__attribute__((address_space(3))) unsigned int*)(unsigned int)(uintptr_t)lds,
        16, 0, 0);
}

// ------------------------------------------------ fused convert (one launch)
__global__ __launch_bounds__(256) void cvt_all(
    const float* __restrict__ hs, const float* __restrict__ wq,
    const float* __restrict__ wk, const float* __restrict__ wv,
    const float* __restrict__ wo,
    unsigned short* __restrict__ o_hs, unsigned short* __restrict__ o_wq,
    unsigned short* __restrict__ o_wk, unsigned short* __restrict__ o_wv,
    unsigned short* __restrict__ o_wo) {
    const int bid = blockIdx.x;
    const float* src; unsigned short* dst; int base;
    if (bid < 2048)      { src = hs; dst = o_hs; base = bid; }
    else if (bid < 3072) { src = wq; dst = o_wq; base = bid - 2048; }
    else if (bid < 4096) { src = wk; dst = o_wk; base = bid - 3072; }
    else if (bid < 5120) { src = wv; dst = o_wv; base = bid - 4096; }
    else                 { src = wo; dst = o_wo; base = bid - 5120; }
    const int i0 = base * 1024 + threadIdx.x;
#pragma unroll
    for (int k = 0; k < 4; k++) {
        const int i = i0 + k * 256;
        float4 v = ((const float4*)src)[i];
        u16x4 pk;
        pk[0] = f2bf(v.x); pk[1] = f2bf(v.y); pk[2] = f2bf(v.z); pk[3] = f2bf(v.w);
        ((u16x4*)dst)[i] = pk;
    }
}

// ------------------------------------------------------- 2-phase GEMM core
// (unchanged — bank-conflict-free, counted vmcnt, 2 barriers/tile)
DEVI void gemm_pipe_core(const unsigned short* __restrict__ A,
                         const unsigned short* __restrict__ Wt,
                         int m0, int n0, char* lds,
                         f32x4 (&acc)[2][2][2][2]) {
    constexpr int K = 2048;
    const int t = threadIdx.x;
    const int w = t >> 6, l = t & 63, lr = l & 15, lk = l >> 4;
    const int wr = w >> 2, wc = w & 3;
    const int sx = lr & 7;
    const int srow = t >> 3, sseg = (t & 7) ^ (srow & 7);
    const unsigned short* aS = A + (size_t)(m0 + srow) * K + sseg * 8;
    const unsigned short* bS = Wt + (size_t)(n0 + srow) * K + sseg * 8;
    char* Bbase = lds + 32768;

#pragma unroll
    for (int qm = 0; qm < 2; qm++)
#pragma unroll
        for (int qn = 0; qn < 2; qn++)
#pragma unroll
            for (int fr = 0; fr < 2; fr++)
#pragma unroll
                for (int fc = 0; fc < 2; fc++)
                    acc[qm][qn][fr][fc] = (f32x4){0.f, 0.f, 0.f, 0.f};

    auto STAGE = [&](int tt, int u) {
        if (tt >= 32) return;
        const int k0 = tt * 64, bb = tt & 1;
        if (u < 4)
            gload16(bS + (size_t)u * 64 * K + k0, Bbase + bb * 32768 + u * 8192 + w * 1024);
        else
            gload16(aS + (size_t)(u - 4) * 64 * K + k0, lds + bb * 16384 + (u - 4) * 8192 + w * 1024);
    };

    STAGE(0, 0); STAGE(0, 1); STAGE(0, 2); STAGE(0, 3); STAGE(0, 4); STAGE(0, 5);
    STAGE(1, 0); STAGE(1, 1); STAGE(1, 2);
    asm volatile("s_waitcnt vmcnt(3)" ::: "memory");
    __builtin_amdgcn_s_barrier();

    for (int kt = 0; kt < 32; ++kt) {
        const int bb = kt & 1;
        const char* Ab = lds + bb * 16384;
        const char* Bb = Bbase + bb * 32768;
        bf16x8 a0[2][2], a1[2][2], b0[2][2], b1[2][2];
#pragma unroll
        for (int fr = 0; fr < 2; fr++)
#pragma unroll
            for (int ks = 0; ks < 2; ks++) {
                a0[fr][ks] = *(const bf16x8*)(Ab + (wr * 64 + fr * 16 + lr) * 128 +
                                              (((ks * 4 + lk) ^ sx) << 4));
                a1[fr][ks] = *(const bf16x8*)(Ab + (wr * 64 + 32 + fr * 16 + lr) * 128 +
                                              (((ks * 4 + lk) ^ sx) << 4));
            }
#pragma unroll
        for (int fc = 0; fc < 2; fc++)
#pragma unroll
            for (int ks = 0; ks < 2; ks++) {
                b0[fc][ks] = *(const bf16x8*)(Bb + (wc * 64 + fc * 16 + lr) * 128 +
                                              (((ks * 4 + lk) ^ sx) << 4));
                b1[fc][ks] = *(const bf16x8*)(Bb + (wc * 64 + 32 + fc * 16 + lr) * 128 +
                                              (((ks * 4 + lk) ^ sx) << 4));
            }
        STAGE(kt + 1, 3); STAGE(kt + 1, 4); STAGE(kt + 1, 5);
        __builtin_amdgcn_s_setprio(1);
#pragma unroll
        for (int ks = 0; ks < 2; ks++)
#pragma unroll
            for (int fr = 0; fr < 2; fr++)
#pragma unroll
                for (int fc = 0; fc < 2; fc++) {
                    acc[0][0][fr][fc] = __builtin_amdgcn_mfma_f32_16x16x32_bf16(
                        a0[fr][ks], b0[fc][ks], acc[0][0][fr][fc], 0, 0, 0);
                    acc[1][0][fr][fc] = __builtin_amdgcn_mfma_f32_16x16x32_bf16(
                        a1[fr][ks], b0[fc][ks], acc[1][0][fr][fc], 0, 0, 0);
                }
        __builtin_amdgcn_s_setprio(0);
        asm volatile("s_waitcnt lgkmcnt(0)" ::: "memory");
        __builtin_amdgcn_s_barrier();
        STAGE(kt + 2, 0); STAGE(kt + 2, 1); STAGE(kt + 2, 2);
        __builtin_amdgcn_s_setprio(1);
#pragma unroll
        for (int ks = 0; ks < 2; ks++)
#pragma unroll
            for (int fr = 0; fr < 2; fr++)
#pragma unroll
                for (int fc = 0; fc < 2; fc++) {
                    acc[0][1][fr][fc] = __builtin_amdgcn_mfma_f32_16x16x32_bf16(
                        a0[fr][ks], b1[fc][ks], acc[0][1][fr][fc], 0, 0, 0);
                    acc[1][1][fr][fc] = __builtin_amdgcn_mfma_f32_16x16x32_bf16(
                        a1[fr][ks], b1[fc][ks], acc[1][1][fr][fc], 0, 0, 0);
                }
        __builtin_amdgcn_s_setprio(0);
        if (kt < 30)       asm volatile("s_waitcnt vmcnt(3)" ::: "memory");
        else if (kt == 30) asm volatile("s_waitcnt vmcnt(0)" ::: "memory");
        __builtin_amdgcn_s_barrier();
    }
}

// qkv: z=0 -> q (fp32), z=1 -> k (fp32), z=2 -> v (bf16, transposed to (B,H,HD,S))
__global__ __launch_bounds__(512, 2) void gemm_qkv(
    const unsigned short* __restrict__ A,
    const unsigned short* __restrict__ Wq16, const unsigned short* __restrict__ Wk16,
    const unsigned short* __restrict__ Wv16,
    const float* __restrict__ bq, const float* __restrict__ bk, const float* __restrict__ bv,
    float* __restrict__ qf, float* __restrict__ kf, unsigned short* __restrict__ Vt) {
    __shared__ char Lds[98304];
    const int bid = blockIdx.x;
    const int nt = bid & 7, rem = bid >> 3;
    const int mt = rem / 3, z = rem % 3;
    const int m0 = mt * 128, n0 = nt * 256;
    const unsigned short* W = (z == 0) ? Wq16 : (z == 1) ? Wk16 : Wv16;
    const float* bias = (z == 0) ? bq : (z == 1) ? bk : bv;

    f32x4 acc[2][2][2][2];
    gemm_pipe_core(A, W, m0, n0, Lds, acc);

    const int t = threadIdx.x, w = t >> 6, l = t & 63, lr = l & 15, lk = l >> 4;
    const int wr = w >> 2, wc = w & 3;
#pragma unroll
    for (int qm = 0; qm < 2; qm++)
#pragma unroll
        for (int qn = 0; qn < 2; qn++)
#pragma unroll
            for (int fr = 0; fr < 2; fr++)
#pragma unroll
                for (int fc = 0; fc < 2; fc++) {
                    const int col = n0 + wc * 64 + qn * 32 + fc * 16 + lr;
                    const int rb = m0 + wr * 64 + qm * 32 + fr * 16 + lk * 4;
                    const float bb = bias[col];
                    if (z == 2) {
                        const int hh = col >> 7, d = col & 127;
                        const int b = rb >> 11, s = rb & 2047;
                        u16x4 pk;
#pragma unroll
                        for (int j = 0; j < 4; j++) pk[j] = f2bf(acc[qm][qn][fr][fc][j] + bb);
                        *(u16x4*)(Vt + ((size_t)((b * 16 + hh) * 128 + d)) * 2048 + s) = pk;
                    } else {
                        float* out = (z == 0) ? qf : kf;
#pragma unroll
                        for (int j = 0; j < 4; j++)
                            out[(size_t)(rb + j) * 2048 + col] = acc[qm][qn][fr][fc][j] + bb;
                    }
                }
}

__global__ __launch_bounds__(512, 2) void gemm_o(
    const unsigned short* __restrict__ A, const unsigned short* __restrict__ W16,
    const float* __restrict__ bo, float* __restrict__ out) {
    __shared__ char Lds[98304];
    const int bid = blockIdx.x;
    const int nt = bid & 7, mt = bid >> 3;
    const int m0 = mt * 128, n0 = nt * 256;

    f32x4 acc[2][2][2][2];
    gemm_pipe_core(A, W16, m0, n0, Lds, acc);

    const int t = threadIdx.x, w = t >> 6, l = t & 63, lr = l & 15, lk = l >> 4;
    const int wr = w >> 2, wc = w & 3;
#pragma unroll
    for (int qm = 0; qm < 2; qm++)
#pragma unroll
        for (int qn = 0; qn < 2; qn++)
#pragma unroll
            for (int fr = 0; fr < 2; fr++)
#pragma unroll
                for (int fc = 0; fc < 2; fc++) {
                    const int col = n0 + wc * 64 + qn * 32 + fc * 16 + lr;
                    const int rb = m0 + wr * 64 + qm * 32 + fr * 16 + lk * 4;
                    const float bb = bo[col];
#pragma unroll
                    for (int j = 0; j < 4; j++)
                        out[(size_t)(rb + j) * 2048 + col] = acc[qm][qn][fr][fc][j] + bb;
                }
}

// ---------------------------------------------------- RMSNorm (full DIM) + RoPE
__global__ __launch_bounds__(256) void norm_rope(
    const float* __restrict__ qf, const float* __restrict__ kf,
    const float* __restrict__ nqw, const float* __restrict__ nkw,
    const float* __restrict__ fc, const float* __restrict__ fs,
    unsigned short* __restrict__ Qr, unsigned short* __restrict__ Kr) {
    const int row = blockIdx.x;
    const int which = blockIdx.y;
    const float* in = which ? kf : qf;
    const float* wv = which ? nkw : nqw;
    unsigned short* out = which ? Kr : Qr;
    const float qs = which ? 1.0f : 0.12751744f;  // 1/sqrt(128) * log2(e)
    const int t = threadIdx.x;
    const float* x = in + (size_t)row * 2048 + t * 8;
    float4 v0 = ((const float4*)x)[0];
    float4 v1 = ((const float4*)x)[1];
    float xv[8] = {v0.x, v0.y, v0.z, v0.w, v1.x, v1.y, v1.z, v1.w};
    float ss = 0.f;
#pragma unroll
    for (int e = 0; e < 8; e++) ss += xv[e] * xv[e];
#pragma unroll
    for (int m = 1; m < 64; m <<= 1) ss += __shfl_xor(ss, m, 64);
    __shared__ float red[4];
    if ((t & 63) == 0) red[t >> 6] = ss;
    __syncthreads();
    const float tot = red[0] + red[1] + red[2] + red[3];
    const float r = rsqrtf(tot * (1.0f / 2048.0f) + 1e-6f);
    const int s = row & 2047, b = row >> 11;
    const int d0 = t * 8, hd0 = d0 & 127, h = d0 >> 7;
    float4 c0 = ((const float4*)(fc + s * 128 + hd0))[0];
    float4 c1 = ((const float4*)(fc + s * 128 + hd0))[1];
    float4 s0 = ((const float4*)(fs + s * 128 + hd0))[0];
    float4 s1 = ((const float4*)(fs + s * 128 + hd0))[1];
    float4 w0 = ((const float4*)(wv + d0))[0];
    float4 w1 = ((const float4*)(wv + d0))[1];
    float wn[8] = {w0.x, w0.y, w0.z, w0.w, w1.x, w1.y, w1.z, w1.w};
    float xn[8];
#pragma unroll
    for (int e = 0; e < 8; e++) xn[e] = xv[e] * wn[e] * r;
    float o[8];
    o[0] = xn[0] * c0.x - xn[1] * s0.y;  o[1] = xn[0] * s0.y + xn[1] * c0.x;
    o[2] = xn[2] * c0.z - xn[3] * s0.w;  o[3] = xn[2] * s0.w + xn[3] * c0.z;
    o[4] = xn[4] * c1.x - xn[5] * s1.y;  o[5] = xn[4] * s1.y + xn[5] * c1.x;
    o[6] = xn[6] * c1.z - xn[7] * s1.w;  o[7] = xn[6] * s1.w + xn[7] * c1.z;
    u16x8 pk;
#pragma unroll
    for (int e = 0; e < 8; e++) pk[e] = f2bf(o[e] * qs);
    *(u16x8*)(out + ((size_t)((b * 16 + h) * 2048 + s)) * 128 + hd0) = pk;
}

// -------------------------------------------------------------- flash attn
// 4 waves x 32 q-rows (block = 128 q rows), 512 blocks -> 2 independent
// blocks/CU (de-phased). Swapped-QK 32x32x16 MFMA. Lane<->lane+32 exchange
// via __shfl_xor(...,32) — the PROVEN formulation from rounds 3-6
// (permlane32_swap reverted: undocumented semantics, 2 failed rounds).
__global__ __launch_bounds__(256, 2) void attn(
    const unsigned short* __restrict__ Qr, const unsigned short* __restrict__ Kr,
    const unsigned short* __restrict__ Vt, unsigned short* __restrict__ Ao) {
    __shared__ unsigned short Kl[2][64 * 128];
    __shared__ unsigned short Vl[2][128 * 64];
    const int t = threadIdx.x, w = t >> 6, l = t & 63;
    const int ql = l & 31, h = l >> 5;
    const int bid = blockIdx.x;
    const int xcd = bid & 7, idx = bid >> 3;
    const int bh = xcd * 4 + (idx >> 4);
    const int q0 = (idx & 15) * 128 + w * 32;
    const int b = bh >> 4, head = bh & 15;

    const unsigned short* Qp = Qr + ((size_t)bh * 2048 + q0) * 128;
    bf16x8 qf[8];
#pragma unroll
    for (int c8 = 0; c8 < 8; c8++)
        qf[c8] = *(const bf16x8*)(Qp + ql * 128 + c8 * 16 + h * 8);

    f32x16 accO[4];
#pragma unroll
    for (int dt = 0; dt < 4; dt++)
#pragma unroll
        for (int r = 0; r < 16; r++) accO[dt][r] = 0.f;
    float mj = -1e30f, ljp = 0.f;

    const unsigned short* Kb = Kr + (size_t)bh * 2048 * 128;
    const unsigned short* Vb = Vt + (size_t)bh * 128 * 2048;
    const int krow = t >> 4, kseg = (t & 15) ^ (krow & 7);  // K: rows w*4..w*4+3 per pass
    const int vrow = t >> 3, vseg = (t & 7) ^ (vrow & 7);   // V: rows w*8..w*8+7 per pass

    auto STAGE = [&](int buf, int kv0) {
        char* kd = (char*)&Kl[buf][0] + w * 1024;
        char* vd = (char*)&Vl[buf][0] + w * 1024;
#pragma unroll
        for (int c = 0; c < 4; c++)
            gload16(Kb + (size_t)(kv0 + c * 16 + krow) * 128 + kseg * 8, kd + c * 4096);
#pragma unroll
        for (int c = 0; c < 4; c++)
            gload16(Vb + (size_t)(c * 32 + vrow) * 2048 + kv0 + vseg * 8, vd + c * 4096);
    };

    const int qx = ql & 7;
    STAGE(0, 0);
    __syncthreads();
    int cur = 0;
    for (int it = 0; it < 32; ++it) {
        if (it < 31) STAGE(cur ^ 1, (it + 1) * 64);
        f32x16 S0, S1;
#pragma unroll
        for (int r = 0; r < 16; r++) { S0[r] = 0.f; S1[r] = 0.f; }
        __builtin_amdgcn_s_setprio(1);
#pragma unroll
        for (int c8 = 0; c8 < 8; c8++) {
            const int sg = ((c8 * 2 + h) ^ qx) << 4;
            bf16x8 k0 = *(const bf16x8*)((const char*)&Kl[cur][0] + ql * 256 + sg);
            bf16x8 k1 = *(const bf16x8*)((const char*)&Kl[cur][0] + (32 + ql) * 256 + sg);
            S0 = __builtin_amdgcn_mfma_f32_32x32x16_bf16(k0, qf[c8], S0, 0, 0, 0);
            S1 = __builtin_amdgcn_mfma_f32_32x32x16_bf16(k1, qf[c8], S1, 0, 0, 0);
        }
        __builtin_amdgcn_s_setprio(0);
        // ---- per-lane online softmax (keys split lane <-> lane^32)
        float mloc = S0[0];
#pragma unroll
        for (int r = 1; r < 16; r++) mloc = fmaxf(mloc, S0[r]);
#pragma unroll
        for (int r = 0; r < 16; r++) mloc = fmaxf(mloc, S1[r]);
        const float mx = fmaxf(mloc, __shfl_xor(mloc, 32, 64));
        if (!__all(mx <= mj + 8.0f)) {          // T13 defer-max, THR=8
            const float mn = fmaxf(mj, mx);
            const float corr = exp2f(mj - mn);
            mj = mn;
            ljp *= corr;
#pragma unroll
            for (int dt = 0; dt < 4; dt++)
#pragma unroll
                for (int r = 0; r < 16; r++) accO[dt][r] *= corr;
        }
        unsigned W[16];
        float lsum = 0.f;
#pragma unroll
        for (int i = 0; i < 8; i++) {
            const float pa = exp2f(S0[2 * i] - mj);
            const float pb = exp2f(S0[2 * i + 1] - mj);
            W[i] = cvtpk(pa, pb);
            lsum += pa + pb;
        }
#pragma unroll
        for (int i = 0; i < 8; i++) {
            const float pa = exp2f(S1[2 * i] - mj);
            const float pb = exp2f(S1[2 * i + 1] - mj);
            W[8 + i] = cvtpk(pa, pb);
            lsum += pa + pb;
        }
        ljp += lsum;
#pragma unroll
        for (int c = 0; c < 2; c++) {
            unsigned X[8];
#pragma unroll
            for (int i = 0; i < 8; i++)
                X[i] = (unsigned)__shfl_xor((int)W[c * 8 + i], 32, 64);
            union U { unsigned u[4]; bf16x8 v; };
            U F, G;
            F.u[0] = h ? X[2] : W[c * 8 + 0];
            F.u[1] = h ? X[3] : W[c * 8 + 1];
            F.u[2] = h ? W[c * 8 + 2] : X[0];
            F.u[3] = h ? W[c * 8 + 3] : X[1];
            G.u[0] = h ? X[6] : W[c * 8 + 4];
            G.u[1] = h ? X[7] : W[c * 8 + 5];
            G.u[2] = h ? W[c * 8 + 6] : X[4];
            G.u[3] = h ? W[c * 8 + 7] : X[5];
            __builtin_amdgcn_s_setprio(1);
#pragma unroll
            for (int dt = 0; dt < 4; dt++) {
                const int sg = (((2 * c) * 2 + h) ^ qx) << 4;
                bf16x8 vf = *(const bf16x8*)((const char*)&Vl[cur][0] + (dt * 32 + ql) * 128 + sg);
                accO[dt] = __builtin_amdgcn_mfma_f32_32x32x16_bf16(vf, F.v, accO[dt], 0, 0, 0);
            }
#pragma unroll
            for (int dt = 0; dt < 4; dt++) {
                const int sg = (((2 * c + 1) * 2 + h) ^ qx) << 4;
                bf16x8 vf = *(const bf16x8*)((const char*)&Vl[cur][0] + (dt * 32 + ql) * 128 + sg);
                accO[dt] = __builtin_amdgcn_mfma_f32_32x32x16_bf16(vf, G.v, accO[dt], 0, 0, 0);
            }
            __builtin_amdgcn_s_setprio(0);
        }
        __syncthreads();
        cur ^= 1;
    }
    const float lj = ljp + __shfl_xor(ljp, 32, 64);
    const float inv = 1.0f / lj;
    unsigned short* ob = Ao + ((size_t)(b * 2048 + q0 + ql)) * 2048 + head * 128;
#pragma unroll
    for (int dt = 0; dt < 4; dt++)
#pragma unroll
        for (int i = 0; i < 8; i++) {
            const float a = accO[dt][2 * i] * inv;
            const float c = accO[dt][2 * i + 1] * inv;
            const int d = dt * 32 + ((2 * i) & 3) + 8 * (i >> 1) + 4 * h;
            *(unsigned*)(ob + d) = cvtpk(a, c);
        }
}

// ------------------------------------------------------------------ launch
extern "C" void kernel_launch(void* const* d_in, const int* in_sizes, int n_in,
                              void* d_out, int out_size, void* d_ws, size_t ws_size,
                              hipStream_t stream) {
    const float* hs  = (const float*)d_in[0];
    const float* fc  = (const float*)d_in[1];
    const float* fs  = (const float*)d_in[2];
    const float* Wq  = (const float*)d_in[3];
    const float* bq  = (const float*)d_in[4];
    const float* Wk  = (const float*)d_in[5];
    const float* bk  = (const float*)d_in[6];
    const float* Wv  = (const float*)d_in[7];
    const float* bv  = (const float*)d_in[8];
    const float* nqw = (const float*)d_in[9];
    const float* nkw = (const float*)d_in[10];
    const float* Wo  = (const float*)d_in[11];
    const float* bo  = (const float*)d_in[12];
    float* out = (float*)d_out;

    char* p = (char*)d_ws;
    unsigned short* hs16 = (unsigned short*)p; p += (size_t)8388608 * 2;
    unsigned short* Wq16 = (unsigned short*)p; p += (size_t)4194304 * 2;
    unsigned short* Wk16 = (unsigned short*)p; p += (size_t)4194304 * 2;
    unsigned short* Wv16 = (unsigned short*)p; p += (size_t)4194304 * 2;
    unsigned short* Wo16 = (unsigned short*)p; p += (size_t)4194304 * 2;
    float* qf = (float*)p;                     p += (size_t)8388608 * 4;
    float* kf = (float*)p;                     p += (size_t)8388608 * 4;
    unsigned short* Qr = (unsigned short*)p;   p += (size_t)8388608 * 2;
    unsigned short* Kr = (unsigned short*)p;   p += (size_t)8388608 * 2;
    unsigned short* Vt = (unsigned short*)p;   p += (size_t)8388608 * 2;
    unsigned short* Ao = (unsigned short*)p;   p += (size_t)8388608 * 2;
    (void)ws_size; (void)in_sizes; (void)n_in; (void)out_size;

    cvt_all<<<6144, 256, 0, stream>>>(hs, Wq, Wk, Wv, Wo,
                                      hs16, Wq16, Wk16, Wv16, Wo16);
    gemm_qkv<<<768, 512, 0, stream>>>(hs16, Wq16, Wk16, Wv16,
                                      bq, bk, bv, qf, kf, Vt);
    norm_rope<<<dim3(4096, 2), 256, 0, stream>>>(qf, kf, nqw, nkw, fc, fs, Qr, Kr);
    attn<<<512, 256, 0, stream>>>(Qr, Kr, Vt, Ao);
    gemm_o<<<256, 512, 0, stream>>>(Ao, Wo16, bo, out);
}